// Round 1
// baseline (4918.725 us; speedup 1.0000x reference)
//
#include <hip/hip_runtime.h>
#include <cstdint>
#include <cstddef>

// Problem constants: B=64, C=3, H=W=64, F=96, K=8, h=w=32, C0=6, P=h*w=1024
// params channels: a[0:6) b[6:12) logpi[12:60) mu[60:108) s[108:156)

__device__ __forceinline__ float sigm(float x){ return 1.0f/(1.0f+__expf(-x)); }

// ---------------- conv1: z(B,3,64,64) checker-gathered as z1(B,6,32,32) -> (B,96,32,32)
__global__ __launch_bounds__(256) void k_conv1(const float* __restrict__ z,
        const float* __restrict__ w, const float* __restrict__ bias,
        float* __restrict__ out)
{
    int blk = blockIdx.x;
    int b = blk / 96, oc = blk % 96;
    __shared__ float tile[6][34*34];
    for (int idx = threadIdx.x; idx < 6*1156; idx += 256) {
        int c = idx / 1156, rem = idx % 1156;
        int r = rem / 34, q = rem % 34;
        int ii = r-1, jj = q-1;
        float v = 0.f;
        if ((unsigned)ii < 32u && (unsigned)jj < 32u) {
            int ch, zr, zc;
            if (c < 3){ ch=c;   zr=2*ii;   zc=2*jj+1; }  // z1[:, :3] = p01
            else      { ch=c-3; zr=2*ii+1; zc=2*jj;   }  // z1[:, 3:] = p10
            v = z[((b*3+ch)*64 + zr)*64 + zc];
        }
        tile[c][rem] = v;
    }
    __syncthreads();
    float bv = bias[oc];
    float acc[4];
    #pragma unroll
    for (int k=0;k<4;++k) acc[k]=bv;
    for (int c=0;c<6;++c){
        const float* wp = w + (oc*6+c)*9;
        float w0=wp[0],w1=wp[1],w2=wp[2],w3=wp[3],w4=wp[4],w5=wp[5],w6=wp[6],w7=wp[7],w8=wp[8];
        #pragma unroll
        for (int k=0;k<4;++k){
            int p = threadIdx.x + 256*k;
            const float* t = &tile[c][(p>>5)*34 + (p&31)];
            acc[k] += w0*t[0]+w1*t[1]+w2*t[2]
                    + w3*t[34]+w4*t[35]+w5*t[36]
                    + w6*t[68]+w7*t[69]+w8*t[70];
        }
    }
    #pragma unroll
    for (int k=0;k<4;++k) out[((size_t)(b*96+oc))*1024 + threadIdx.x + 256*k] = acc[k];
}

// ---------------- generic 3x3 SAME conv on 32x32, IC->OC, block per (b,oc)
__global__ __launch_bounds__(256) void k_conv3x3(const float* __restrict__ x,
    const float* __restrict__ w, const float* __restrict__ bias,
    float* __restrict__ out, int IC, int OC)
{
    int blk = blockIdx.x;
    int b = blk / OC, oc = blk % OC;
    __shared__ float tile[34*34];
    float bv = bias[oc];
    float acc[4];
    #pragma unroll
    for (int k=0;k<4;++k) acc[k]=bv;
    for (int ic=0; ic<IC; ++ic){
        __syncthreads();
        for (int idx=threadIdx.x; idx<1156; idx+=256){
            int r=idx/34, q=idx%34; int ii=r-1, jj=q-1;
            tile[idx] = ((unsigned)ii<32u && (unsigned)jj<32u)
                      ? x[((size_t)(b*IC+ic))*1024 + ii*32+jj] : 0.f;
        }
        __syncthreads();
        const float* wp = w + ((size_t)(oc*IC+ic))*9;
        float w0=wp[0],w1=wp[1],w2=wp[2],w3=wp[3],w4=wp[4],w5=wp[5],w6=wp[6],w7=wp[7],w8=wp[8];
        #pragma unroll
        for (int k=0;k<4;++k){
            int p = threadIdx.x + 256*k;
            const float* t = &tile[(p>>5)*34 + (p&31)];
            acc[k] += w0*t[0]+w1*t[1]+w2*t[2]
                    + w3*t[34]+w4*t[35]+w5*t[36]
                    + w6*t[68]+w7*t[69]+w8*t[70];
        }
    }
    #pragma unroll
    for (int k=0;k<4;++k) out[((size_t)(b*OC+oc))*1024 + threadIdx.x + 256*k] = acc[k];
}

// ---------------- gating: x += ga * sigmoid(gb), g is (B,192,1024)
__global__ __launch_bounds__(256) void k_gate(float* __restrict__ x, const float* __restrict__ g)
{
    int idx = blockIdx.x*256 + threadIdx.x;   // exactly 64*96*1024 threads
    int b = idx / 98304; int rem = idx - b*98304;
    float ga = g[((size_t)b*192)*1024 + rem];
    float gb = g[((size_t)(b*192+96))*1024 + rem];
    x[idx] += ga * sigm(gb);
}

// ---------------- per-sample LayerNorm over 96*32*32, elementwise affine (g,b are (96,32,32))
__global__ __launch_bounds__(1024) void k_ln(const float* __restrict__ x,
    const float* __restrict__ gw, const float* __restrict__ bw, float* __restrict__ out)
{
    int b = blockIdx.x;
    const float* xb = x + (size_t)b*98304;
    float s=0.f, ss=0.f;
    for (int e=threadIdx.x; e<98304; e+=1024){ float v=xb[e]; s+=v; ss+=v*v; }
    #pragma unroll
    for (int o=32;o>0;o>>=1){ s += __shfl_down(s,o,64); ss += __shfl_down(ss,o,64); }
    __shared__ float rs[16], rss[16]; __shared__ float smu, srstd;
    int wid = threadIdx.x>>6;
    if ((threadIdx.x&63)==0){ rs[wid]=s; rss[wid]=ss; }
    __syncthreads();
    if (threadIdx.x==0){
        float S=0.f, SS=0.f;
        for (int i=0;i<16;++i){ S+=rs[i]; SS+=rss[i]; }
        float mu = S/98304.f;
        float var = SS/98304.f - mu*mu;
        smu = mu; srstd = rsqrtf(var + 1e-5f);
    }
    __syncthreads();
    float mu=smu, r=srstd;
    float* ob = out + (size_t)b*98304;
    for (int e=threadIdx.x; e<98304; e+=1024)
        ob[e] = (xb[e]-mu)*r*gw[e] + bw[e];
}

// ---------------- qkv: xln (B,96,1024) -> Q (B,1024,96), K (B,96,1024), V (B,1024,96)
__global__ __launch_bounds__(256) void k_qkv(const float* __restrict__ xln,
    const float* __restrict__ w, const float* __restrict__ bias,
    float* __restrict__ Q, float* __restrict__ Kb, float* __restrict__ V)
{
    int b = blockIdx.x >> 6; int pt = blockIdx.x & 63; int p0 = pt*16;
    __shared__ float xt[16][97];
    for (int idx=threadIdx.x; idx<16*96; idx+=256){
        int pl = idx & 15, f = idx >> 4;
        xt[pl][f] = xln[(size_t)b*98304 + f*1024 + p0 + pl];
    }
    __syncthreads();
    for (int oi=threadIdx.x; oi<16*288; oi+=256){
        int pl = oi & 15, n = oi >> 4;
        const float* wr = w + n*96;
        float acc = bias[n];
        #pragma unroll 8
        for (int f=0; f<96; ++f) acc += xt[pl][f]*wr[f];
        int p = p0+pl;
        if (n < 96)       Q[((size_t)(b*1024+p))*96 + n]            = acc;
        else if (n < 192) Kb[((size_t)(b*96 + (n-96)))*1024 + p]    = acc;
        else              V[((size_t)(b*1024+p))*96 + (n-192)]      = acc;
    }
}

// ---------------- attention: per (b, 8-query tile); scores in LDS, K staged in 64-key tiles
__global__ __launch_bounds__(256) void k_attn(const float* __restrict__ Q,
    const float* __restrict__ Kb, const float* __restrict__ V, float* __restrict__ O)
{
    int b = blockIdx.x >> 7; int qt = blockIdx.x & 127; int q0 = qt*8;
    __shared__ float qs[8][96];
    __shared__ float ps[8][1028];
    __shared__ float kt[96*64];
    __shared__ float rinv[8];
    for (int idx=threadIdx.x; idx<8*96; idx+=256){
        int ql = idx/96, f = idx%96;
        qs[ql][f] = Q[((size_t)(b*1024+q0+ql))*96 + f];
    }
    for (int jt=0; jt<16; ++jt){
        __syncthreads();
        for (int idx=threadIdx.x; idx<96*64; idx+=256)
            kt[idx] = Kb[((size_t)(b*96 + (idx>>6)))*1024 + jt*64 + (idx&63)];
        __syncthreads();
        for (int oi=threadIdx.x; oi<8*64; oi+=256){
            int qq = oi>>6, jl = oi&63;
            const float* qr = qs[qq];
            const float* kc = kt + jl;
            float acc = 0.f;
            #pragma unroll 16
            for (int f=0; f<96; ++f) acc += qr[f]*kc[f<<6];
            ps[qq][jt*64+jl] = acc * 0.10206207262f;   // 1/sqrt(96)
        }
    }
    __syncthreads();
    {   // softmax per row: 32 lanes per row
        int r = threadIdx.x>>5, l = threadIdx.x&31;
        float m = -1e30f;
        for (int jj=l; jj<1024; jj+=32) m = fmaxf(m, ps[r][jj]);
        #pragma unroll
        for (int o=16;o>0;o>>=1) m = fmaxf(m, __shfl_down(m,o,32));
        m = __shfl(m, 0, 32);
        float ssum = 0.f;
        for (int jj=l; jj<1024; jj+=32){ float e = __expf(ps[r][jj]-m); ps[r][jj]=e; ssum+=e; }
        #pragma unroll
        for (int o=16;o>0;o>>=1) ssum += __shfl_down(ssum,o,32);
        if (l==0) rinv[r] = 1.0f/ssum;
    }
    __syncthreads();
    float acc[3] = {0.f,0.f,0.f};
    int q_[3], f_[3];
    #pragma unroll
    for (int k=0;k<3;++k){ int oi = threadIdx.x+256*k; q_[k]=oi/96; f_[k]=oi%96; }
    const float* vb = V + (size_t)b*1024*96;
    for (int j=0;j<1024;++j){
        const float* vr = vb + (size_t)j*96;
        #pragma unroll
        for (int k=0;k<3;++k) acc[k] += ps[q_[k]][j] * vr[f_[k]];
    }
    #pragma unroll
    for (int k=0;k<3;++k)
        O[((size_t)(b*1024+q0+q_[k]))*96 + f_[k]] = acc[k] * rinv[q_[k]];
}

// ---------------- proj + residual gate: x2 = xln + ga*sigmoid(gb), output NCHW (B,96,1024)
__global__ __launch_bounds__(256) void k_proj(const float* __restrict__ O,
    const float* __restrict__ xln, const float* __restrict__ w,
    const float* __restrict__ bias, float* __restrict__ x2)
{
    int b = blockIdx.x >> 6; int pt = blockIdx.x & 63; int p0 = pt*16;
    __shared__ float ot[16][97];
    for (int idx=threadIdx.x; idx<16*96; idx+=256){
        int pl = idx/96, f = idx%96;
        ot[pl][f] = O[((size_t)(b*1024+p0+pl))*96 + f];
    }
    __syncthreads();
    for (int oi=threadIdx.x; oi<16*96; oi+=256){
        int pl = oi & 15, c = oi >> 4;
        const float* wa = w + c*96;
        const float* wb = w + (c+96)*96;
        float a = bias[c], bg = bias[c+96];
        #pragma unroll 8
        for (int f=0; f<96; ++f){ float xv = ot[pl][f]; a += xv*wa[f]; bg += xv*wb[f]; }
        size_t idx2 = ((size_t)(b*96+c))*1024 + p0+pl;
        x2[idx2] = xln[idx2] + a*sigm(bg);
    }
}

// ---------------- copy incoming log_df_dz into output (atomicAdd target)
__global__ void k_initlog(const float* __restrict__ lin, float* __restrict__ lout)
{
    if (threadIdx.x < 64) lout[threadIdx.x] = lin[threadIdx.x];
}

// ---------------- mixture transform + merge + log-det
__global__ __launch_bounds__(256) void k_mix(const float* __restrict__ z,
    const float* __restrict__ params, const float* __restrict__ a_ls_p,
    const float* __restrict__ a_b_p, float* __restrict__ out_z, float* __restrict__ out_log)
{
    int b = blockIdx.x >> 2;
    int pix = (blockIdx.x & 3)*256 + threadIdx.x;
    int i = pix >> 5, j = pix & 31;
    float als = a_ls_p[0], abv = a_b_p[0];
    const float* pb = params + (size_t)b*156*1024;
    float logacc = 0.f;

    // passthrough (z1 positions are identity in the merged output)
    #pragma unroll
    for (int c=0;c<3;++c){
        int idx01 = ((b*3+c)*64 + 2*i)*64 + 2*j+1;
        int idx10 = ((b*3+c)*64 + 2*i+1)*64 + 2*j;
        out_z[idx01] = z[idx01];
        out_z[idx10] = z[idx10];
    }

    for (int c0=0;c0<6;++c0){
        float z0v = (c0<3) ? z[((b*3+c0)*64 + 2*i)*64 + 2*j]
                           : z[((b*3+(c0-3))*64 + 2*i+1)*64 + 2*j+1];
        float a_raw = pb[(c0)*1024 + pix];
        float bco   = pb[(6+c0)*1024 + pix];
        float lp[8], mu[8], sv[8];
        float m1 = -1e30f;
        #pragma unroll
        for (int k=0;k<8;++k){
            lp[k] = pb[(12 + k*6 + c0)*1024 + pix];
            mu[k] = pb[(60 + k*6 + c0)*1024 + pix];
            sv[k] = pb[(108 + k*6 + c0)*1024 + pix];
            m1 = fmaxf(m1, lp[k]);
        }
        float se = 0.f;
        #pragma unroll
        for (int k=0;k<8;++k) se += __expf(lp[k]-m1);
        float lse = m1 + __logf(se);
        float xm = 0.f, mt = -1e30f;
        float t[8];
        #pragma unroll
        for (int k=0;k<8;++k){
            float lpn = lp[k] - lse;
            float u = (z0v - mu[k]) * __expf(-sv[k]);
            float au = fabsf(u);
            xm += __expf(lpn) * (1.f/(1.f+__expf(-u)));
            float lss = -(au + 2.f*log1pf(__expf(-au)));   // logsig(u)+logsig(-u)
            float tk = lpn - sv[k] + lss;
            t[k] = tk; mt = fmaxf(mt, tk);
        }
        float se2 = 0.f;
        #pragma unroll
        for (int k=0;k<8;++k) se2 += __expf(t[k]-mt);
        logacc += mt + __logf(se2);
        xm = fminf(fmaxf(xm, 1e-6f), 1.f-1e-6f);
        float lx = __logf(xm), l1x = log1pf(-xm);
        logacc += -lx - l1x;
        float aa = tanhf(a_raw)*als + abv;
        float z0n = (lx - l1x)*__expf(aa) + bco;
        logacc += aa;
        int oidx = (c0<3) ? ((b*3+c0)*64 + 2*i)*64 + 2*j
                          : ((b*3+(c0-3))*64 + 2*i+1)*64 + 2*j+1;
        out_z[oidx] = z0n;
    }

    #pragma unroll
    for (int o=32;o>0;o>>=1) logacc += __shfl_down(logacc, o, 64);
    __shared__ float part[4];
    if ((threadIdx.x&63)==0) part[threadIdx.x>>6] = logacc;
    __syncthreads();
    if (threadIdx.x==0){
        atomicAdd(out_log + b, part[0]+part[1]+part[2]+part[3]);
    }
}

extern "C" void kernel_launch(void* const* d_in, const int* in_sizes, int n_in,
                              void* d_out, int out_size, void* d_ws, size_t ws_size,
                              hipStream_t stream)
{
    const float* z     = (const float*)d_in[0];
    const float* logdf = (const float*)d_in[1];
    const float* c1w   = (const float*)d_in[2];
    const float* c1b   = (const float*)d_in[3];
    const float* gw    = (const float*)d_in[4];
    const float* gcb   = (const float*)d_in[5];
    const float* ln1g  = (const float*)d_in[6];
    const float* ln1b  = (const float*)d_in[7];
    const float* qkvw  = (const float*)d_in[8];
    const float* qkvb  = (const float*)d_in[9];
    const float* pw    = (const float*)d_in[10];
    const float* pbb   = (const float*)d_in[11];
    const float* ln2g  = (const float*)d_in[12];
    const float* ln2b  = (const float*)d_in[13];
    const float* c2w   = (const float*)d_in[14];
    const float* c2b   = (const float*)d_in[15];
    const float* als   = (const float*)d_in[16];
    const float* ab    = (const float*)d_in[17];

    float* out_z   = (float*)d_out;
    float* out_log = out_z + 786432;

    // workspace layout (floats), total 31457280 floats = 125.8 MB, with lifetime reuse
    float* ws     = (float*)d_ws;
    float* x1     = ws;                 // (B,96,1024)            [region A]
    float* g      = ws + 6291456;       // (B,192,1024) gconv out [region B0+B1]
    float* xln    = g;                  // (B,96,1024) LN1 out    [B0] (g dead after gate)
    float* Kbuf   = ws + 12582912;      // (B,96,1024)            [B1]
    float* Q      = x1;                 // (B,1024,96)            [A]  (x1 dead after LN1)
    float* V      = ws + 18874368;      // (B,1024,96)
    float* O      = ws + 25165824;      // (B,1024,96)
    float* x2     = x1;                 // (B,96,1024)            [A]  (Q dead after attn)
    float* xln2   = g;                  // (B,96,1024) LN2 out    [B0] (xln dead after proj)
    float* params = ws + 18874368;      // (B,156,1024)           over V+O (dead after proj)

    k_conv1  <<<64*96 , 256, 0, stream>>>(z, c1w, c1b, x1);
    k_conv3x3<<<64*192, 256, 0, stream>>>(x1, gw, gcb, g, 96, 192);
    k_gate   <<<24576 , 256, 0, stream>>>(x1, g);
    k_ln     <<<64    ,1024, 0, stream>>>(x1, ln1g, ln1b, xln);
    k_qkv    <<<64*64 , 256, 0, stream>>>(xln, qkvw, qkvb, Q, Kbuf, V);
    k_attn   <<<64*128, 256, 0, stream>>>(Q, Kbuf, V, O);
    k_proj   <<<64*64 , 256, 0, stream>>>(O, xln, pw, pbb, x2);
    k_ln     <<<64    ,1024, 0, stream>>>(x2, ln2g, ln2b, xln2);
    k_conv3x3<<<64*156, 256, 0, stream>>>(xln2, c2w, c2b, params, 96, 156);
    k_initlog<<<1     ,  64, 0, stream>>>(logdf, out_log);
    k_mix    <<<64*4  , 256, 0, stream>>>(z, params, als, ab, out_z, out_log);
}

// Round 2
// 2932.955 us; speedup vs baseline: 1.6771x; 1.6771x over previous
//
#include <hip/hip_runtime.h>
#include <cstdint>
#include <cstddef>

// Problem constants: B=64, C=3, H=W=64, F=96, K=8, h=w=32, C0=6, P=h*w=1024
// params channels: a[0:6) b[6:12) logpi[12:60) mu[60:108) s[108:156)

typedef unsigned short u16;
typedef __attribute__((ext_vector_type(8))) short short8;
typedef __attribute__((ext_vector_type(4))) float f32x4;

__device__ __forceinline__ float sigm(float x){ return 1.0f/(1.0f+__expf(-x)); }

__device__ __forceinline__ u16 f2bf(float f){
    unsigned int u = __float_as_uint(f);
    u += 0x7fffu + ((u >> 16) & 1u);
    return (u16)(u >> 16);
}

// ---------------- conv1: z(B,3,64,64) checker-gathered as z1(B,6,32,32) -> (B,96,32,32)
__global__ __launch_bounds__(256) void k_conv1(const float* __restrict__ z,
        const float* __restrict__ w, const float* __restrict__ bias,
        float* __restrict__ out)
{
    int blk = blockIdx.x;
    int b = blk / 96, oc = blk % 96;
    __shared__ float tile[6][34*34];
    for (int idx = threadIdx.x; idx < 6*1156; idx += 256) {
        int c = idx / 1156, rem = idx % 1156;
        int r = rem / 34, q = rem % 34;
        int ii = r-1, jj = q-1;
        float v = 0.f;
        if ((unsigned)ii < 32u && (unsigned)jj < 32u) {
            int ch, zr, zc;
            if (c < 3){ ch=c;   zr=2*ii;   zc=2*jj+1; }  // z1[:, :3] = p01
            else      { ch=c-3; zr=2*ii+1; zc=2*jj;   }  // z1[:, 3:] = p10
            v = z[((b*3+ch)*64 + zr)*64 + zc];
        }
        tile[c][rem] = v;
    }
    __syncthreads();
    float bv = bias[oc];
    float acc[4];
    #pragma unroll
    for (int k=0;k<4;++k) acc[k]=bv;
    for (int c=0;c<6;++c){
        const float* wp = w + (oc*6+c)*9;
        float w0=wp[0],w1=wp[1],w2=wp[2],w3=wp[3],w4=wp[4],w5=wp[5],w6=wp[6],w7=wp[7],w8=wp[8];
        #pragma unroll
        for (int k=0;k<4;++k){
            int p = threadIdx.x + 256*k;
            const float* t = &tile[c][(p>>5)*34 + (p&31)];
            acc[k] += w0*t[0]+w1*t[1]+w2*t[2]
                    + w3*t[34]+w4*t[35]+w5*t[36]
                    + w6*t[68]+w7*t[69]+w8*t[70];
        }
    }
    #pragma unroll
    for (int k=0;k<4;++k) out[((size_t)(b*96+oc))*1024 + threadIdx.x + 256*k] = acc[k];
}

// ---------------- generic 3x3 SAME conv on 32x32, IC->OC, block per (b,oc)
__global__ __launch_bounds__(256) void k_conv3x3(const float* __restrict__ x,
    const float* __restrict__ w, const float* __restrict__ bias,
    float* __restrict__ out, int IC, int OC)
{
    int blk = blockIdx.x;
    int b = blk / OC, oc = blk % OC;
    __shared__ float tile[34*34];
    float bv = bias[oc];
    float acc[4];
    #pragma unroll
    for (int k=0;k<4;++k) acc[k]=bv;
    for (int ic=0; ic<IC; ++ic){
        __syncthreads();
        for (int idx=threadIdx.x; idx<1156; idx+=256){
            int r=idx/34, q=idx%34; int ii=r-1, jj=q-1;
            tile[idx] = ((unsigned)ii<32u && (unsigned)jj<32u)
                      ? x[((size_t)(b*IC+ic))*1024 + ii*32+jj] : 0.f;
        }
        __syncthreads();
        const float* wp = w + ((size_t)(oc*IC+ic))*9;
        float w0=wp[0],w1=wp[1],w2=wp[2],w3=wp[3],w4=wp[4],w5=wp[5],w6=wp[6],w7=wp[7],w8=wp[8];
        #pragma unroll
        for (int k=0;k<4;++k){
            int p = threadIdx.x + 256*k;
            const float* t = &tile[(p>>5)*34 + (p&31)];
            acc[k] += w0*t[0]+w1*t[1]+w2*t[2]
                    + w3*t[34]+w4*t[35]+w5*t[36]
                    + w6*t[68]+w7*t[69]+w8*t[70];
        }
    }
    #pragma unroll
    for (int k=0;k<4;++k) out[((size_t)(b*OC+oc))*1024 + threadIdx.x + 256*k] = acc[k];
}

// ---------------- gating: x += ga * sigmoid(gb), g is (B,192,1024)
__global__ __launch_bounds__(256) void k_gate(float* __restrict__ x, const float* __restrict__ g)
{
    int idx = blockIdx.x*256 + threadIdx.x;   // exactly 64*96*1024 threads
    int b = idx / 98304; int rem = idx - b*98304;
    float ga = g[((size_t)b*192)*1024 + rem];
    float gb = g[((size_t)(b*192+96))*1024 + rem];
    x[idx] += ga * sigm(gb);
}

// ---------------- per-sample LayerNorm over 96*32*32, elementwise affine (g,b are (96,32,32))
__global__ __launch_bounds__(1024) void k_ln(const float* __restrict__ x,
    const float* __restrict__ gw, const float* __restrict__ bw, float* __restrict__ out)
{
    int b = blockIdx.x;
    const float* xb = x + (size_t)b*98304;
    float s=0.f, ss=0.f;
    for (int e=threadIdx.x; e<98304; e+=1024){ float v=xb[e]; s+=v; ss+=v*v; }
    #pragma unroll
    for (int o=32;o>0;o>>=1){ s += __shfl_down(s,o,64); ss += __shfl_down(ss,o,64); }
    __shared__ float rs[16], rss[16]; __shared__ float smu, srstd;
    int wid = threadIdx.x>>6;
    if ((threadIdx.x&63)==0){ rs[wid]=s; rss[wid]=ss; }
    __syncthreads();
    if (threadIdx.x==0){
        float S=0.f, SS=0.f;
        for (int i=0;i<16;++i){ S+=rs[i]; SS+=rss[i]; }
        float mu = S/98304.f;
        float var = SS/98304.f - mu*mu;
        smu = mu; srstd = rsqrtf(var + 1e-5f);
    }
    __syncthreads();
    float mu=smu, r=srstd;
    float* ob = out + (size_t)b*98304;
    for (int e=threadIdx.x; e<98304; e+=1024)
        ob[e] = (xb[e]-mu)*r*gw[e] + bw[e];
}

// ---------------- qkv: xln (B,96,1024) -> bf16 Q (B,1024,96), K (B,1024,96), Vt tiled (B,16,96,64)
__global__ __launch_bounds__(256) void k_qkv(const float* __restrict__ xln,
    const float* __restrict__ w, const float* __restrict__ bias,
    u16* __restrict__ Qb, u16* __restrict__ Kbb, u16* __restrict__ Vtb)
{
    int b = blockIdx.x >> 6; int pt = blockIdx.x & 63; int p0 = pt*16;
    __shared__ float xt[16][97];
    for (int idx=threadIdx.x; idx<16*96; idx+=256){
        int pl = idx & 15, f = idx >> 4;
        xt[pl][f] = xln[(size_t)b*98304 + f*1024 + p0 + pl];
    }
    __syncthreads();
    for (int oi=threadIdx.x; oi<16*288; oi+=256){
        int pl = oi & 15, n = oi >> 4;
        const float* wr = w + n*96;
        float acc = bias[n];
        #pragma unroll 8
        for (int f=0; f<96; ++f) acc += xt[pl][f]*wr[f];
        int p = p0+pl;
        u16 v = f2bf(acc);
        if (n < 96)       Qb[((size_t)(b*1024+p))*96 + n]           = v;
        else if (n < 192) Kbb[((size_t)(b*1024+p))*96 + (n-96)]     = v;
        else {
            int f = n-192;
            Vtb[((size_t)((b*16 + (p>>6))*96 + f))*64 + (p&63)]     = v;
        }
    }
}

// ---------------- flash attention, bf16 MFMA 16x16x32.
// block = (b, 64-query tile), 4 waves, wave owns 16 queries. 16 key-tiles of 64.
__global__ __launch_bounds__(256,4) void k_attn(const u16* __restrict__ Qb,
    const u16* __restrict__ Kbb, const u16* __restrict__ Vtb, float* __restrict__ O)
{
    int b  = blockIdx.x >> 4;
    int q0 = (blockIdx.x & 15) * 64;
    int tid = threadIdx.x;
    int w  = tid >> 6;
    int lane = tid & 63;
    int cc = lane & 15;      // col / m index
    int gg = lane >> 4;      // quad

    __shared__ __align__(16) u16 Ks[64][104];      // [key][feat], 208B rows
    __shared__ __align__(16) u16 Vs[96][72];       // [feat][key], 144B rows
    __shared__ __align__(16) u16 Ps[4][16][72];    // per-wave P [q][key], 144B rows

    // preload Q fragments: A[m=cc][k = ks*32 + 8*gg + j]
    short8 qf[3];
    const u16* qrow = Qb + ((size_t)(b*1024 + q0 + 16*w + cc))*96;
    #pragma unroll
    for (int ks=0; ks<3; ++ks)
        qf[ks] = *reinterpret_cast<const short8*>(qrow + ks*32 + 8*gg);

    f32x4 Oacc[6];
    #pragma unroll
    for (int ft=0; ft<6; ++ft) Oacc[ft] = (f32x4){0.f,0.f,0.f,0.f};
    float m_r[4] = {-1e30f,-1e30f,-1e30f,-1e30f};
    float l_r[4] = {0.f,0.f,0.f,0.f};

    const u16* Kbase = Kbb + (size_t)b*1024*96;
    const u16* Vbase = Vtb + (size_t)b*16*96*64;
    const float scale = 0.10206207262f;   // 1/sqrt(96)

    for (int jt=0; jt<16; ++jt){
        __syncthreads();   // previous tile's MFMA reads done
        // stage K tile: 64 keys x 96 feats, contiguous 12288B in global
        const u16* kt = Kbase + (size_t)jt*64*96;
        #pragma unroll
        for (int ii=0; ii<3; ++ii){
            int i = tid + 256*ii;
            int key = i / 12, fo = (i % 12) * 8;
            *reinterpret_cast<short8*>(&Ks[key][fo]) =
                *reinterpret_cast<const short8*>(kt + key*96 + fo);
        }
        // stage V tile (already [feat][key64] in global, contiguous 12288B)
        const u16* vt = Vbase + (size_t)jt*96*64;
        #pragma unroll
        for (int ii=0; ii<3; ++ii){
            int i = tid + 256*ii;
            int f = i >> 3, ko = (i & 7) * 8;
            *reinterpret_cast<short8*>(&Vs[f][ko]) =
                *reinterpret_cast<const short8*>(vt + f*64 + ko);
        }
        __syncthreads();

        // S = Q K^T for 16q x 64k
        f32x4 Sacc[4];
        #pragma unroll
        for (int t=0; t<4; ++t) Sacc[t] = (f32x4){0.f,0.f,0.f,0.f};
        #pragma unroll
        for (int ks=0; ks<3; ++ks){
            short8 a = qf[ks];
            #pragma unroll
            for (int t=0; t<4; ++t){
                short8 bb = *reinterpret_cast<const short8*>(&Ks[t*16+cc][ks*32+8*gg]);
                Sacc[t] = __builtin_amdgcn_mfma_f32_16x16x32_bf16(a, bb, Sacc[t], 0,0,0);
            }
        }
        // online softmax; row r lives at (gg, reg r) across 16 lanes (cc)
        float alpha[4];
        #pragma unroll
        for (int r=0; r<4; ++r){
            float s0 = Sacc[0][r]*scale, s1 = Sacc[1][r]*scale,
                  s2 = Sacc[2][r]*scale, s3 = Sacc[3][r]*scale;
            float mt = fmaxf(fmaxf(s0,s1), fmaxf(s2,s3));
            #pragma unroll
            for (int msk=1; msk<16; msk<<=1) mt = fmaxf(mt, __shfl_xor(mt, msk, 64));
            float mnew = fmaxf(m_r[r], mt);
            alpha[r] = __expf(m_r[r] - mnew);
            m_r[r] = mnew;
            float p0 = __expf(s0-mnew), p1 = __expf(s1-mnew),
                  p2 = __expf(s2-mnew), p3 = __expf(s3-mnew);
            Sacc[0][r]=p0; Sacc[1][r]=p1; Sacc[2][r]=p2; Sacc[3][r]=p3;
            float rs = p0+p1+p2+p3;
            #pragma unroll
            for (int msk=1; msk<16; msk<<=1) rs += __shfl_xor(rs, msk, 64);
            l_r[r] = l_r[r]*alpha[r] + rs;
        }
        // rescale O accumulator
        #pragma unroll
        for (int ft=0; ft<6; ++ft){
            #pragma unroll
            for (int r=0; r<4; ++r) Oacc[ft][r] *= alpha[r];
        }
        // P (C-layout) -> wave-private LDS [q][key] for A-layout reads
        #pragma unroll
        for (int t=0; t<4; ++t){
            #pragma unroll
            for (int r=0; r<4; ++r)
                Ps[w][4*gg + r][t*16 + cc] = f2bf(Sacc[t][r]);
        }
        // O += P V   (A-frag from Ps, B-frag from Vs)
        #pragma unroll
        for (int kk=0; kk<2; ++kk){
            short8 pa = *reinterpret_cast<const short8*>(&Ps[w][cc][kk*32 + 8*gg]);
            #pragma unroll
            for (int ft=0; ft<6; ++ft){
                short8 vb = *reinterpret_cast<const short8*>(&Vs[ft*16+cc][kk*32+8*gg]);
                Oacc[ft] = __builtin_amdgcn_mfma_f32_16x16x32_bf16(pa, vb, Oacc[ft], 0,0,0);
            }
        }
    }

    // epilogue: O /= l, write fp32 (B,1024,96)
    float linv[4];
    #pragma unroll
    for (int r=0; r<4; ++r) linv[r] = 1.0f / l_r[r];
    #pragma unroll
    for (int ft=0; ft<6; ++ft){
        #pragma unroll
        for (int r=0; r<4; ++r)
            O[((size_t)(b*1024 + q0 + 16*w + 4*gg + r))*96 + ft*16 + cc] = Oacc[ft][r]*linv[r];
    }
}

// ---------------- proj + residual gate: x2 = xln + ga*sigmoid(gb), output NCHW (B,96,1024)
__global__ __launch_bounds__(256) void k_proj(const float* __restrict__ O,
    const float* __restrict__ xln, const float* __restrict__ w,
    const float* __restrict__ bias, float* __restrict__ x2)
{
    int b = blockIdx.x >> 6; int pt = blockIdx.x & 63; int p0 = pt*16;
    __shared__ float ot[16][97];
    for (int idx=threadIdx.x; idx<16*96; idx+=256){
        int pl = idx/96, f = idx%96;
        ot[pl][f] = O[((size_t)(b*1024+p0+pl))*96 + f];
    }
    __syncthreads();
    for (int oi=threadIdx.x; oi<16*96; oi+=256){
        int pl = oi & 15, c = oi >> 4;
        const float* wa = w + c*96;
        const float* wb = w + (c+96)*96;
        float a = bias[c], bg = bias[c+96];
        #pragma unroll 8
        for (int f=0; f<96; ++f){ float xv = ot[pl][f]; a += xv*wa[f]; bg += xv*wb[f]; }
        size_t idx2 = ((size_t)(b*96+c))*1024 + p0+pl;
        x2[idx2] = xln[idx2] + a*sigm(bg);
    }
}

// ---------------- copy incoming log_df_dz into output (atomicAdd target)
__global__ void k_initlog(const float* __restrict__ lin, float* __restrict__ lout)
{
    if (threadIdx.x < 64) lout[threadIdx.x] = lin[threadIdx.x];
}

// ---------------- mixture transform + merge + log-det
__global__ __launch_bounds__(256) void k_mix(const float* __restrict__ z,
    const float* __restrict__ params, const float* __restrict__ a_ls_p,
    const float* __restrict__ a_b_p, float* __restrict__ out_z, float* __restrict__ out_log)
{
    int b = blockIdx.x >> 2;
    int pix = (blockIdx.x & 3)*256 + threadIdx.x;
    int i = pix >> 5, j = pix & 31;
    float als = a_ls_p[0], abv = a_b_p[0];
    const float* pb = params + (size_t)b*156*1024;
    float logacc = 0.f;

    // passthrough (z1 positions are identity in the merged output)
    #pragma unroll
    for (int c=0;c<3;++c){
        int idx01 = ((b*3+c)*64 + 2*i)*64 + 2*j+1;
        int idx10 = ((b*3+c)*64 + 2*i+1)*64 + 2*j;
        out_z[idx01] = z[idx01];
        out_z[idx10] = z[idx10];
    }

    for (int c0=0;c0<6;++c0){
        float z0v = (c0<3) ? z[((b*3+c0)*64 + 2*i)*64 + 2*j]
                           : z[((b*3+(c0-3))*64 + 2*i+1)*64 + 2*j+1];
        float a_raw = pb[(c0)*1024 + pix];
        float bco   = pb[(6+c0)*1024 + pix];
        float lp[8], mu[8], sv[8];
        float m1 = -1e30f;
        #pragma unroll
        for (int k=0;k<8;++k){
            lp[k] = pb[(12 + k*6 + c0)*1024 + pix];
            mu[k] = pb[(60 + k*6 + c0)*1024 + pix];
            sv[k] = pb[(108 + k*6 + c0)*1024 + pix];
            m1 = fmaxf(m1, lp[k]);
        }
        float se = 0.f;
        #pragma unroll
        for (int k=0;k<8;++k) se += __expf(lp[k]-m1);
        float lse = m1 + __logf(se);
        float xm = 0.f, mt = -1e30f;
        float t[8];
        #pragma unroll
        for (int k=0;k<8;++k){
            float lpn = lp[k] - lse;
            float u = (z0v - mu[k]) * __expf(-sv[k]);
            float au = fabsf(u);
            xm += __expf(lpn) * (1.f/(1.f+__expf(-u)));
            float lss = -(au + 2.f*log1pf(__expf(-au)));   // logsig(u)+logsig(-u)
            float tk = lpn - sv[k] + lss;
            t[k] = tk; mt = fmaxf(mt, tk);
        }
        float se2 = 0.f;
        #pragma unroll
        for (int k=0;k<8;++k) se2 += __expf(t[k]-mt);
        logacc += mt + __logf(se2);
        xm = fminf(fmaxf(xm, 1e-6f), 1.f-1e-6f);
        float lx = __logf(xm), l1x = log1pf(-xm);
        logacc += -lx - l1x;
        float aa = tanhf(a_raw)*als + abv;
        float z0n = (lx - l1x)*__expf(aa) + bco;
        logacc += aa;
        int oidx = (c0<3) ? ((b*3+c0)*64 + 2*i)*64 + 2*j
                          : ((b*3+(c0-3))*64 + 2*i+1)*64 + 2*j+1;
        out_z[oidx] = z0n;
    }

    #pragma unroll
    for (int o=32;o>0;o>>=1) logacc += __shfl_down(logacc, o, 64);
    __shared__ float part[4];
    if ((threadIdx.x&63)==0) part[threadIdx.x>>6] = logacc;
    __syncthreads();
    if (threadIdx.x==0){
        atomicAdd(out_log + b, part[0]+part[1]+part[2]+part[3]);
    }
}

extern "C" void kernel_launch(void* const* d_in, const int* in_sizes, int n_in,
                              void* d_out, int out_size, void* d_ws, size_t ws_size,
                              hipStream_t stream)
{
    const float* z     = (const float*)d_in[0];
    const float* logdf = (const float*)d_in[1];
    const float* c1w   = (const float*)d_in[2];
    const float* c1b   = (const float*)d_in[3];
    const float* gw    = (const float*)d_in[4];
    const float* gcb   = (const float*)d_in[5];
    const float* ln1g  = (const float*)d_in[6];
    const float* ln1b  = (const float*)d_in[7];
    const float* qkvw  = (const float*)d_in[8];
    const float* qkvb  = (const float*)d_in[9];
    const float* pw    = (const float*)d_in[10];
    const float* pbb   = (const float*)d_in[11];
    const float* ln2g  = (const float*)d_in[12];
    const float* ln2b  = (const float*)d_in[13];
    const float* c2w   = (const float*)d_in[14];
    const float* c2b   = (const float*)d_in[15];
    const float* als   = (const float*)d_in[16];
    const float* ab    = (const float*)d_in[17];

    float* out_z   = (float*)d_out;
    float* out_log = out_z + 786432;

    // workspace layout (float units), peak 29,097,984 floats = 116.4 MB
    float* ws     = (float*)d_ws;
    float* x1     = ws;                  // (B,96,1024)              [A: 0 .. 6291456)
    float* g      = ws + 6291456;        // (B,192,1024) gconv out   [B0+B1)
    float* xln    = g;                   // (B,96,1024) LN1 out      [B0] (g dead after gate)
    u16*   Qb     = (u16*)(ws + 18874368);   // bf16 (B,1024,96)     [C0: 3145728 floats]
    u16*   Kbb    = (u16*)(ws + 22020096);   // bf16 (B,1024,96)     [C1]
    u16*   Vtb    = (u16*)(ws + 25165824);   // bf16 (B,16,96,64)    [C2]
    float* O      = x1;                  // (B,1024,96) fp32         [A] (x1 dead after LN1)
    float* x2     = ws + 12582912;       // (B,96,1024)              [B1]
    float* xln2   = g;                   // (B,96,1024) LN2 out      [B0] (xln dead after proj)
    float* params = ws + 18874368;       // (B,156,1024)             [C] (Q/K/V dead after attn)

    k_conv1  <<<64*96 , 256, 0, stream>>>(z, c1w, c1b, x1);
    k_conv3x3<<<64*192, 256, 0, stream>>>(x1, gw, gcb, g, 96, 192);
    k_gate   <<<24576 , 256, 0, stream>>>(x1, g);
    k_ln     <<<64    ,1024, 0, stream>>>(x1, ln1g, ln1b, xln);
    k_qkv    <<<64*64 , 256, 0, stream>>>(xln, qkvw, qkvb, Qb, Kbb, Vtb);
    k_attn   <<<64*16 , 256, 0, stream>>>(Qb, Kbb, Vtb, O);
    k_proj   <<<64*64 , 256, 0, stream>>>(O, xln, pw, pbb, x2);
    k_ln     <<<64    ,1024, 0, stream>>>(x2, ln2g, ln2b, xln2);
    k_conv3x3<<<64*156, 256, 0, stream>>>(xln2, c2w, c2b, params, 96, 156);
    k_initlog<<<1     ,  64, 0, stream>>>(logdf, out_log);
    k_mix    <<<64*4  , 256, 0, stream>>>(z, params, als, ab, out_z, out_log);
}

// Round 3
// 911.455 us; speedup vs baseline: 5.3966x; 3.2179x over previous
//
#include <hip/hip_runtime.h>
#include <cstdint>
#include <cstddef>

// Problem constants: B=64, C=3, H=W=64, F=96, K=8, h=w=32, C0=6, P=h*w=1024
// params channels: a[0:6) b[6:12) logpi[12:60) mu[60:108) s[108:156)

typedef unsigned short u16;
typedef __attribute__((ext_vector_type(8))) short short8;
typedef __attribute__((ext_vector_type(4))) float f32x4;

__device__ __forceinline__ float sigm(float x){ return 1.0f/(1.0f+__expf(-x)); }

__device__ __forceinline__ u16 f2bf(float f){
    unsigned int u = __float_as_uint(f);
    u += 0x7fffu + ((u >> 16) & 1u);
    return (u16)(u >> 16);
}

// ---------------- weight repack: W (OC,96,3,3) fp32 -> Wt[tap][oc][ic] bf16, oc padded to OCP
__global__ __launch_bounds__(256) void k_wrep(const float* __restrict__ w,
    u16* __restrict__ wt, int OCR, int OCP)
{
    int idx = blockIdx.x*256 + threadIdx.x;
    if (idx >= 9*OCP*96) return;
    int tap = idx / (OCP*96);
    int rem = idx - tap*OCP*96;
    int oc = rem / 96, ic = rem % 96;
    wt[idx] = (oc < OCR) ? f2bf(w[(size_t)(oc*96+ic)*9 + tap]) : (u16)0;
}

// ---------------- conv1: z(B,3,64,64) checker-gathered as z1(B,6,32,32) -> (B,96,32,32)
// writes fp32 channel-major x1 AND bf16 pixel-major x1b
__global__ __launch_bounds__(256) void k_conv1(const float* __restrict__ z,
        const float* __restrict__ w, const float* __restrict__ bias,
        float* __restrict__ out, u16* __restrict__ outb)
{
    int blk = blockIdx.x;
    int b = blk / 96, oc = blk % 96;
    __shared__ float tile[6][34*34];
    for (int idx = threadIdx.x; idx < 6*1156; idx += 256) {
        int c = idx / 1156, rem = idx % 1156;
        int r = rem / 34, q = rem % 34;
        int ii = r-1, jj = q-1;
        float v = 0.f;
        if ((unsigned)ii < 32u && (unsigned)jj < 32u) {
            int ch, zr, zc;
            if (c < 3){ ch=c;   zr=2*ii;   zc=2*jj+1; }  // z1[:, :3] = p01
            else      { ch=c-3; zr=2*ii+1; zc=2*jj;   }  // z1[:, 3:] = p10
            v = z[((b*3+ch)*64 + zr)*64 + zc];
        }
        tile[c][rem] = v;
    }
    __syncthreads();
    float bv = bias[oc];
    float acc[4];
    #pragma unroll
    for (int k=0;k<4;++k) acc[k]=bv;
    for (int c=0;c<6;++c){
        const float* wp = w + (oc*6+c)*9;
        float w0=wp[0],w1=wp[1],w2=wp[2],w3=wp[3],w4=wp[4],w5=wp[5],w6=wp[6],w7=wp[7],w8=wp[8];
        #pragma unroll
        for (int k=0;k<4;++k){
            int p = threadIdx.x + 256*k;
            const float* t = &tile[c][(p>>5)*34 + (p&31)];
            acc[k] += w0*t[0]+w1*t[1]+w2*t[2]
                    + w3*t[34]+w4*t[35]+w5*t[36]
                    + w6*t[68]+w7*t[69]+w8*t[70];
        }
    }
    #pragma unroll
    for (int k=0;k<4;++k){
        int p = threadIdx.x + 256*k;
        out[((size_t)(b*96+oc))*1024 + p] = acc[k];
        outb[((size_t)(b*1024+p))*96 + oc] = f2bf(acc[k]);
    }
}

// ---------------- MFMA implicit-GEMM 3x3 SAME conv on 32x32, IC=96.
// Xpb: bf16 [b][1024][96]; Wt: bf16 [9][OCP][96]; block = (b, 128-pixel group), 4 waves,
// wave = 32 pixels (2 MFMA row-tiles) x OCT oc-tiles.
// GATE: OCT=12 (OC=192), out = x1 (B,96,1024), x1 += ga*sigm(gb).
// else: OCT=10 (OC=156 padded 160), out = params (B,156,1024), += bias.
template<int OCT, bool GATE>
__global__ __launch_bounds__(256,3) void k_convm(const u16* __restrict__ Xpb,
    const u16* __restrict__ Wt, const float* __restrict__ bias,
    float* __restrict__ out, int OC_real)
{
    constexpr int OCP = OCT*16;
    int b    = blockIdx.x >> 3;
    int pblk = blockIdx.x & 7;
    int tid  = threadIdx.x;
    int w = tid >> 6, lane = tid & 63;
    int cc = lane & 15, gg = lane >> 4;

    __shared__ __align__(16) u16 Ws[OCP][104];

    f32x4 acc[2][OCT];
    #pragma unroll
    for (int u=0;u<2;++u)
        #pragma unroll
        for (int t=0;t<OCT;++t) acc[u][t] = (f32x4){0.f,0.f,0.f,0.f};

    int base = pblk*128 + w*32;          // multiple of 32 -> both subtiles same image row
    int ia = base >> 5;                  // image row of A-fragment pixels
    const u16* xb = Xpb + (size_t)b*1024*96;

    for (int tap=0; tap<9; ++tap){
        int dr = tap/3 - 1, dc = tap%3 - 1;
        __syncthreads();
        const u16* wt = Wt + (size_t)tap*OCP*96;
        for (int c = tid; c < OCP*12; c += 256){
            int oc = c/12, ico = (c%12)*8;
            *reinterpret_cast<short8*>(&Ws[oc][ico]) =
                *reinterpret_cast<const short8*>(wt + oc*96 + ico);
        }
        __syncthreads();

        int ii = ia + dr;
        int jj0 = cc + dc, jj1 = cc + 16 + dc;
        bool rv = ((unsigned)ii < 32u);
        bool v0 = rv && ((unsigned)jj0 < 32u);
        bool v1 = rv && ((unsigned)jj1 < 32u);
        const u16* ar0 = xb + (ptrdiff_t)(ii*32 + jj0)*96 + 8*gg;
        const u16* ar1 = xb + (ptrdiff_t)(ii*32 + jj1)*96 + 8*gg;

        #pragma unroll
        for (int ks=0; ks<3; ++ks){
            short8 a0 = {0,0,0,0,0,0,0,0};
            short8 a1 = {0,0,0,0,0,0,0,0};
            if (v0) a0 = *reinterpret_cast<const short8*>(ar0 + ks*32);
            if (v1) a1 = *reinterpret_cast<const short8*>(ar1 + ks*32);
            #pragma unroll
            for (int t=0; t<OCT; ++t){
                short8 bb = *reinterpret_cast<const short8*>(&Ws[t*16+cc][ks*32+8*gg]);
                acc[0][t] = __builtin_amdgcn_mfma_f32_16x16x32_bf16(a0, bb, acc[0][t], 0,0,0);
                acc[1][t] = __builtin_amdgcn_mfma_f32_16x16x32_bf16(a1, bb, acc[1][t], 0,0,0);
            }
        }
    }

    // epilogue: C/D layout col=cc (oc), row=gg*4+r (pixel within 16-tile)
    if constexpr (GATE){
        #pragma unroll
        for (int u=0;u<2;++u){
            int p0 = base + u*16 + gg*4;
            #pragma unroll
            for (int t=0;t<6;++t){
                int oca = t*16+cc;
                float ba = bias[oca], bbv = bias[oca+96];
                float* xp = out + ((size_t)(b*96 + oca))*1024 + p0;
                #pragma unroll
                for (int r=0;r<4;++r){
                    float va = acc[u][t][r]   + ba;
                    float vb = acc[u][t+6][r] + bbv;
                    xp[r] += va * sigm(vb);
                }
            }
        }
    } else {
        #pragma unroll
        for (int u=0;u<2;++u){
            int p0 = base + u*16 + gg*4;
            #pragma unroll
            for (int t=0;t<OCT;++t){
                int oc = t*16+cc;
                if (oc < OC_real){
                    float bv = bias[oc];
                    float* op = out + ((size_t)b*OC_real + oc)*1024 + p0;
                    #pragma unroll
                    for (int r=0;r<4;++r) op[r] = acc[u][t][r] + bv;
                }
            }
        }
    }
}

// ---------------- per-sample LayerNorm over 96*32*32, elementwise affine (g,b are (96,32,32))
// optionally also writes bf16 pixel-major [b][pix][c]
__global__ __launch_bounds__(1024) void k_ln(const float* __restrict__ x,
    const float* __restrict__ gw, const float* __restrict__ bw,
    float* __restrict__ out, u16* __restrict__ outb)
{
    int b = blockIdx.x;
    const float* xb = x + (size_t)b*98304;
    float s=0.f, ss=0.f;
    for (int e=threadIdx.x; e<98304; e+=1024){ float v=xb[e]; s+=v; ss+=v*v; }
    #pragma unroll
    for (int o=32;o>0;o>>=1){ s += __shfl_down(s,o,64); ss += __shfl_down(ss,o,64); }
    __shared__ float rs[16], rss[16]; __shared__ float smu, srstd;
    int wid = threadIdx.x>>6;
    if ((threadIdx.x&63)==0){ rs[wid]=s; rss[wid]=ss; }
    __syncthreads();
    if (threadIdx.x==0){
        float S=0.f, SS=0.f;
        for (int i=0;i<16;++i){ S+=rs[i]; SS+=rss[i]; }
        float mu = S/98304.f;
        float var = SS/98304.f - mu*mu;
        smu = mu; srstd = rsqrtf(var + 1e-5f);
    }
    __syncthreads();
    float mu=smu, r=srstd;
    float* ob = out + (size_t)b*98304;
    u16* obb = outb ? outb + (size_t)b*98304 : nullptr;
    for (int e=threadIdx.x; e<98304; e+=1024){
        float val = (xb[e]-mu)*r*gw[e] + bw[e];
        ob[e] = val;
        if (obb) obb[(size_t)(e & 1023)*96 + (e >> 10)] = f2bf(val);
    }
}

// ---------------- qkv: xln (B,96,1024) -> bf16 Q (B,1024,96), K (B,1024,96), Vt tiled (B,16,96,64)
__global__ __launch_bounds__(256) void k_qkv(const float* __restrict__ xln,
    const float* __restrict__ w, const float* __restrict__ bias,
    u16* __restrict__ Qb, u16* __restrict__ Kbb, u16* __restrict__ Vtb)
{
    int b = blockIdx.x >> 6; int pt = blockIdx.x & 63; int p0 = pt*16;
    __shared__ float xt[16][97];
    for (int idx=threadIdx.x; idx<16*96; idx+=256){
        int pl = idx & 15, f = idx >> 4;
        xt[pl][f] = xln[(size_t)b*98304 + f*1024 + p0 + pl];
    }
    __syncthreads();
    for (int oi=threadIdx.x; oi<16*288; oi+=256){
        int pl = oi & 15, n = oi >> 4;
        const float* wr = w + n*96;
        float acc = bias[n];
        #pragma unroll 8
        for (int f=0; f<96; ++f) acc += xt[pl][f]*wr[f];
        int p = p0+pl;
        u16 v = f2bf(acc);
        if (n < 96)       Qb[((size_t)(b*1024+p))*96 + n]           = v;
        else if (n < 192) Kbb[((size_t)(b*1024+p))*96 + (n-96)]     = v;
        else {
            int f = n-192;
            Vtb[((size_t)((b*16 + (p>>6))*96 + f))*64 + (p&63)]     = v;
        }
    }
}

// ---------------- flash attention, bf16 MFMA 16x16x32.
// block = (b, 64-query tile), 4 waves, wave owns 16 queries. 16 key-tiles of 64.
__global__ __launch_bounds__(256,4) void k_attn(const u16* __restrict__ Qb,
    const u16* __restrict__ Kbb, const u16* __restrict__ Vtb, float* __restrict__ O)
{
    int b  = blockIdx.x >> 4;
    int q0 = (blockIdx.x & 15) * 64;
    int tid = threadIdx.x;
    int w  = tid >> 6;
    int lane = tid & 63;
    int cc = lane & 15;      // col / m index
    int gg = lane >> 4;      // quad

    __shared__ __align__(16) u16 Ks[64][104];      // [key][feat], 208B rows
    __shared__ __align__(16) u16 Vs[96][72];       // [feat][key], 144B rows
    __shared__ __align__(16) u16 Ps[4][16][72];    // per-wave P [q][key], 144B rows

    // preload Q fragments: A[m=cc][k = ks*32 + 8*gg + j]
    short8 qf[3];
    const u16* qrow = Qb + ((size_t)(b*1024 + q0 + 16*w + cc))*96;
    #pragma unroll
    for (int ks=0; ks<3; ++ks)
        qf[ks] = *reinterpret_cast<const short8*>(qrow + ks*32 + 8*gg);

    f32x4 Oacc[6];
    #pragma unroll
    for (int ft=0; ft<6; ++ft) Oacc[ft] = (f32x4){0.f,0.f,0.f,0.f};
    float m_r[4] = {-1e30f,-1e30f,-1e30f,-1e30f};
    float l_r[4] = {0.f,0.f,0.f,0.f};

    const u16* Kbase = Kbb + (size_t)b*1024*96;
    const u16* Vbase = Vtb + (size_t)b*16*96*64;
    const float scale = 0.10206207262f;   // 1/sqrt(96)

    for (int jt=0; jt<16; ++jt){
        __syncthreads();   // previous tile's MFMA reads done
        // stage K tile: 64 keys x 96 feats, contiguous 12288B in global
        const u16* kt = Kbase + (size_t)jt*64*96;
        #pragma unroll
        for (int ii=0; ii<3; ++ii){
            int i = tid + 256*ii;
            int key = i / 12, fo = (i % 12) * 8;
            *reinterpret_cast<short8*>(&Ks[key][fo]) =
                *reinterpret_cast<const short8*>(kt + key*96 + fo);
        }
        // stage V tile (already [feat][key64] in global, contiguous 12288B)
        const u16* vt = Vbase + (size_t)jt*96*64;
        #pragma unroll
        for (int ii=0; ii<3; ++ii){
            int i = tid + 256*ii;
            int f = i >> 3, ko = (i & 7) * 8;
            *reinterpret_cast<short8*>(&Vs[f][ko]) =
                *reinterpret_cast<const short8*>(vt + f*64 + ko);
        }
        __syncthreads();

        // S = Q K^T for 16q x 64k
        f32x4 Sacc[4];
        #pragma unroll
        for (int t=0; t<4; ++t) Sacc[t] = (f32x4){0.f,0.f,0.f,0.f};
        #pragma unroll
        for (int ks=0; ks<3; ++ks){
            short8 a = qf[ks];
            #pragma unroll
            for (int t=0; t<4; ++t){
                short8 bb = *reinterpret_cast<const short8*>(&Ks[t*16+cc][ks*32+8*gg]);
                Sacc[t] = __builtin_amdgcn_mfma_f32_16x16x32_bf16(a, bb, Sacc[t], 0,0,0);
            }
        }
        // online softmax; row r lives at (gg, reg r) across 16 lanes (cc)
        float alpha[4];
        #pragma unroll
        for (int r=0; r<4; ++r){
            float s0 = Sacc[0][r]*scale, s1 = Sacc[1][r]*scale,
                  s2 = Sacc[2][r]*scale, s3 = Sacc[3][r]*scale;
            float mt = fmaxf(fmaxf(s0,s1), fmaxf(s2,s3));
            #pragma unroll
            for (int msk=1; msk<16; msk<<=1) mt = fmaxf(mt, __shfl_xor(mt, msk, 64));
            float mnew = fmaxf(m_r[r], mt);
            alpha[r] = __expf(m_r[r] - mnew);
            m_r[r] = mnew;
            float p0 = __expf(s0-mnew), p1 = __expf(s1-mnew),
                  p2 = __expf(s2-mnew), p3 = __expf(s3-mnew);
            Sacc[0][r]=p0; Sacc[1][r]=p1; Sacc[2][r]=p2; Sacc[3][r]=p3;
            float rs = p0+p1+p2+p3;
            #pragma unroll
            for (int msk=1; msk<16; msk<<=1) rs += __shfl_xor(rs, msk, 64);
            l_r[r] = l_r[r]*alpha[r] + rs;
        }
        // rescale O accumulator
        #pragma unroll
        for (int ft=0; ft<6; ++ft){
            #pragma unroll
            for (int r=0; r<4; ++r) Oacc[ft][r] *= alpha[r];
        }
        // P (C-layout) -> wave-private LDS [q][key] for A-layout reads
        #pragma unroll
        for (int t=0; t<4; ++t){
            #pragma unroll
            for (int r=0; r<4; ++r)
                Ps[w][4*gg + r][t*16 + cc] = f2bf(Sacc[t][r]);
        }
        // O += P V   (A-frag from Ps, B-frag from Vs)
        #pragma unroll
        for (int kk=0; kk<2; ++kk){
            short8 pa = *reinterpret_cast<const short8*>(&Ps[w][cc][kk*32 + 8*gg]);
            #pragma unroll
            for (int ft=0; ft<6; ++ft){
                short8 vb = *reinterpret_cast<const short8*>(&Vs[ft*16+cc][kk*32+8*gg]);
                Oacc[ft] = __builtin_amdgcn_mfma_f32_16x16x32_bf16(pa, vb, Oacc[ft], 0,0,0);
            }
        }
    }

    // epilogue: O /= l, write fp32 (B,1024,96)
    float linv[4];
    #pragma unroll
    for (int r=0; r<4; ++r) linv[r] = 1.0f / l_r[r];
    #pragma unroll
    for (int ft=0; ft<6; ++ft){
        #pragma unroll
        for (int r=0; r<4; ++r)
            O[((size_t)(b*1024 + q0 + 16*w + 4*gg + r))*96 + ft*16 + cc] = Oacc[ft][r]*linv[r];
    }
}

// ---------------- proj + residual gate: x2 = xln + ga*sigmoid(gb), output NCHW (B,96,1024)
__global__ __launch_bounds__(256) void k_proj(const float* __restrict__ O,
    const float* __restrict__ xln, const float* __restrict__ w,
    const float* __restrict__ bias, float* __restrict__ x2)
{
    int b = blockIdx.x >> 6; int pt = blockIdx.x & 63; int p0 = pt*16;
    __shared__ float ot[16][97];
    for (int idx=threadIdx.x; idx<16*96; idx+=256){
        int pl = idx/96, f = idx%96;
        ot[pl][f] = O[((size_t)(b*1024+p0+pl))*96 + f];
    }
    __syncthreads();
    for (int oi=threadIdx.x; oi<16*96; oi+=256){
        int pl = oi & 15, c = oi >> 4;
        const float* wa = w + c*96;
        const float* wb = w + (c+96)*96;
        float a = bias[c], bg = bias[c+96];
        #pragma unroll 8
        for (int f=0; f<96; ++f){ float xv = ot[pl][f]; a += xv*wa[f]; bg += xv*wb[f]; }
        size_t idx2 = ((size_t)(b*96+c))*1024 + p0+pl;
        x2[idx2] = xln[idx2] + a*sigm(bg);
    }
}

// ---------------- copy incoming log_df_dz into output (atomicAdd target)
__global__ void k_initlog(const float* __restrict__ lin, float* __restrict__ lout)
{
    if (threadIdx.x < 64) lout[threadIdx.x] = lin[threadIdx.x];
}

// ---------------- mixture transform + merge + log-det
__global__ __launch_bounds__(256) void k_mix(const float* __restrict__ z,
    const float* __restrict__ params, const float* __restrict__ a_ls_p,
    const float* __restrict__ a_b_p, float* __restrict__ out_z, float* __restrict__ out_log)
{
    int b = blockIdx.x >> 2;
    int pix = (blockIdx.x & 3)*256 + threadIdx.x;
    int i = pix >> 5, j = pix & 31;
    float als = a_ls_p[0], abv = a_b_p[0];
    const float* pb = params + (size_t)b*156*1024;
    float logacc = 0.f;

    // passthrough (z1 positions are identity in the merged output)
    #pragma unroll
    for (int c=0;c<3;++c){
        int idx01 = ((b*3+c)*64 + 2*i)*64 + 2*j+1;
        int idx10 = ((b*3+c)*64 + 2*i+1)*64 + 2*j;
        out_z[idx01] = z[idx01];
        out_z[idx10] = z[idx10];
    }

    for (int c0=0;c0<6;++c0){
        float z0v = (c0<3) ? z[((b*3+c0)*64 + 2*i)*64 + 2*j]
                           : z[((b*3+(c0-3))*64 + 2*i+1)*64 + 2*j+1];
        float a_raw = pb[(c0)*1024 + pix];
        float bco   = pb[(6+c0)*1024 + pix];
        float lp[8], mu[8], sv[8];
        float m1 = -1e30f;
        #pragma unroll
        for (int k=0;k<8;++k){
            lp[k] = pb[(12 + k*6 + c0)*1024 + pix];
            mu[k] = pb[(60 + k*6 + c0)*1024 + pix];
            sv[k] = pb[(108 + k*6 + c0)*1024 + pix];
            m1 = fmaxf(m1, lp[k]);
        }
        float se = 0.f;
        #pragma unroll
        for (int k=0;k<8;++k) se += __expf(lp[k]-m1);
        float lse = m1 + __logf(se);
        float xm = 0.f, mt = -1e30f;
        float t[8];
        #pragma unroll
        for (int k=0;k<8;++k){
            float lpn = lp[k] - lse;
            float u = (z0v - mu[k]) * __expf(-sv[k]);
            float au = fabsf(u);
            xm += __expf(lpn) * (1.f/(1.f+__expf(-u)));
            float lss = -(au + 2.f*log1pf(__expf(-au)));   // logsig(u)+logsig(-u)
            float tk = lpn - sv[k] + lss;
            t[k] = tk; mt = fmaxf(mt, tk);
        }
        float se2 = 0.f;
        #pragma unroll
        for (int k=0;k<8;++k) se2 += __expf(t[k]-mt);
        logacc += mt + __logf(se2);
        xm = fminf(fmaxf(xm, 1e-6f), 1.f-1e-6f);
        float lx = __logf(xm), l1x = log1pf(-xm);
        logacc += -lx - l1x;
        float aa = tanhf(a_raw)*als + abv;
        float z0n = (lx - l1x)*__expf(aa) + bco;
        logacc += aa;
        int oidx = (c0<3) ? ((b*3+c0)*64 + 2*i)*64 + 2*j
                          : ((b*3+(c0-3))*64 + 2*i+1)*64 + 2*j+1;
        out_z[oidx] = z0n;
    }

    #pragma unroll
    for (int o=32;o>0;o>>=1) logacc += __shfl_down(logacc, o, 64);
    __shared__ float part[4];
    if ((threadIdx.x&63)==0) part[threadIdx.x>>6] = logacc;
    __syncthreads();
    if (threadIdx.x==0){
        atomicAdd(out_log + b, part[0]+part[1]+part[2]+part[3]);
    }
}

extern "C" void kernel_launch(void* const* d_in, const int* in_sizes, int n_in,
                              void* d_out, int out_size, void* d_ws, size_t ws_size,
                              hipStream_t stream)
{
    const float* z     = (const float*)d_in[0];
    const float* logdf = (const float*)d_in[1];
    const float* c1w   = (const float*)d_in[2];
    const float* c1b   = (const float*)d_in[3];
    const float* gw    = (const float*)d_in[4];
    const float* gcb   = (const float*)d_in[5];
    const float* ln1g  = (const float*)d_in[6];
    const float* ln1b  = (const float*)d_in[7];
    const float* qkvw  = (const float*)d_in[8];
    const float* qkvb  = (const float*)d_in[9];
    const float* pw    = (const float*)d_in[10];
    const float* pbb   = (const float*)d_in[11];
    const float* ln2g  = (const float*)d_in[12];
    const float* ln2b  = (const float*)d_in[13];
    const float* c2w   = (const float*)d_in[14];
    const float* c2b   = (const float*)d_in[15];
    const float* als   = (const float*)d_in[16];
    const float* ab    = (const float*)d_in[17];

    float* out_z   = (float*)d_out;
    float* out_log = out_z + 786432;

    // workspace layout (float units), peak 25,317,888 floats = 101.3 MB
    float* ws     = (float*)d_ws;
    float* x1     = ws;                        // (B,96,1024) fp32; conv1 out -> gated in-place
    u16*   x1b    = (u16*)(ws + 6291456);      // (B,1024,96) bf16 pixel-major (gconv input)
    u16*   Wg     = (u16*)(ws + 9437184);      // [9][192][96] bf16   (82944 floats)
    u16*   W2     = (u16*)(ws + 9520128);      // [9][160][96] bf16   (69120 floats)
    float* xln    = ws + 9589248;              // (B,96,1024) LN1 out fp32
    float* x2     = ws + 15880704;             // (B,96,1024) proj out / LN2 in-place
    u16*   xln2b  = (u16*)(ws + 22172160);     // (B,1024,96) bf16 pixel-major (conv2 input)
    u16*   Qb     = x1b;                       // reuse (x1b dead after gconv)
    u16*   Kbb    = (u16*)(ws + 15880704);     // in x2 span (x2 written after attn)
    u16*   Vtb    = (u16*)(ws + 19026432);     // in x2 span
    float* O      = x1;                        // (B,1024,96) fp32 (x1 dead after LN1)
    float* params = ws + 9589248;              // (B,156,1024) over xln+x2-low (dead at conv2)

    k_wrep   <<<648 , 256, 0, stream>>>(gw,  Wg, 192, 192);
    k_wrep   <<<540 , 256, 0, stream>>>(c2w, W2, 156, 160);
    k_conv1  <<<6144, 256, 0, stream>>>(z, c1w, c1b, x1, x1b);
    k_convm<12,true> <<<512, 256, 0, stream>>>(x1b, Wg, gcb, x1, 192);
    k_ln     <<<64  ,1024, 0, stream>>>(x1, ln1g, ln1b, xln, nullptr);
    k_qkv    <<<4096, 256, 0, stream>>>(xln, qkvw, qkvb, Qb, Kbb, Vtb);
    k_attn   <<<1024, 256, 0, stream>>>(Qb, Kbb, Vtb, O);
    k_proj   <<<4096, 256, 0, stream>>>(O, xln, pw, pbb, x2);
    k_ln     <<<64  ,1024, 0, stream>>>(x2, ln2g, ln2b, x2, xln2b);   // in-place fp32 + bf16
    k_convm<10,false><<<512, 256, 0, stream>>>(xln2b, W2, c2b, params, 156);
    k_initlog<<<1   ,  64, 0, stream>>>(logdf, out_log);
    k_mix    <<<256 , 256, 0, stream>>>(z, params, als, ab, out_z, out_log);
}

// Round 4
// 689.879 us; speedup vs baseline: 7.1298x; 1.3212x over previous
//
#include <hip/hip_runtime.h>
#include <cstdint>
#include <cstddef>

// Problem constants: B=64, C=3, H=W=64, F=96, K=8, h=w=32, C0=6, P=h*w=1024
// params channels: a[0:6) b[6:12) logpi[12:60) mu[60:108) s[108:156)

typedef unsigned short u16;
typedef __attribute__((ext_vector_type(8))) short short8;
typedef __attribute__((ext_vector_type(4))) float f32x4;

__device__ __forceinline__ float sigm(float x){ return 1.0f/(1.0f+__expf(-x)); }

__device__ __forceinline__ u16 f2bf(float f){
    unsigned int u = __float_as_uint(f);
    u += 0x7fffu + ((u >> 16) & 1u);
    return (u16)(u >> 16);
}
__device__ __forceinline__ float bf2f(u16 v){
    unsigned int u = ((unsigned int)v) << 16;
    return __uint_as_float(u);
}

// ---------------- weight repack: W (OC,96,3,3) fp32 -> Wt[tap][oc][ic] bf16, oc padded to OCP
__global__ __launch_bounds__(256) void k_wrep(const float* __restrict__ w,
    u16* __restrict__ wt, int OCR, int OCP)
{
    int idx = blockIdx.x*256 + threadIdx.x;
    if (idx >= 9*OCP*96) return;
    int tap = idx / (OCP*96);
    int rem = idx - tap*OCP*96;
    int oc = rem / 96, ic = rem % 96;
    wt[idx] = (oc < OCR) ? f2bf(w[(size_t)(oc*96+ic)*9 + tap]) : (u16)0;
}

// ---------------- matrix repack: W (N,96) fp32 -> bf16 (N,96)
__global__ __launch_bounds__(256) void k_wrepm(const float* __restrict__ w,
    u16* __restrict__ wt, int n)
{
    int idx = blockIdx.x*256 + threadIdx.x;
    if (idx < n) wt[idx] = f2bf(w[idx]);
}

// ---------------- conv1: z(B,3,64,64) checker-gathered as z1(B,6,32,32) -> (B,96,32,32)
// writes fp32 channel-major x1 AND bf16 pixel-major x1b
__global__ __launch_bounds__(256) void k_conv1(const float* __restrict__ z,
        const float* __restrict__ w, const float* __restrict__ bias,
        float* __restrict__ out, u16* __restrict__ outb)
{
    int blk = blockIdx.x;
    int b = blk / 96, oc = blk % 96;
    __shared__ float tile[6][34*34];
    for (int idx = threadIdx.x; idx < 6*1156; idx += 256) {
        int c = idx / 1156, rem = idx % 1156;
        int r = rem / 34, q = rem % 34;
        int ii = r-1, jj = q-1;
        float v = 0.f;
        if ((unsigned)ii < 32u && (unsigned)jj < 32u) {
            int ch, zr, zc;
            if (c < 3){ ch=c;   zr=2*ii;   zc=2*jj+1; }  // z1[:, :3] = p01
            else      { ch=c-3; zr=2*ii+1; zc=2*jj;   }  // z1[:, 3:] = p10
            v = z[((b*3+ch)*64 + zr)*64 + zc];
        }
        tile[c][rem] = v;
    }
    __syncthreads();
    float bv = bias[oc];
    float acc[4];
    #pragma unroll
    for (int k=0;k<4;++k) acc[k]=bv;
    for (int c=0;c<6;++c){
        const float* wp = w + (oc*6+c)*9;
        float w0=wp[0],w1=wp[1],w2=wp[2],w3=wp[3],w4=wp[4],w5=wp[5],w6=wp[6],w7=wp[7],w8=wp[8];
        #pragma unroll
        for (int k=0;k<4;++k){
            int p = threadIdx.x + 256*k;
            const float* t = &tile[c][(p>>5)*34 + (p&31)];
            acc[k] += w0*t[0]+w1*t[1]+w2*t[2]
                    + w3*t[34]+w4*t[35]+w5*t[36]
                    + w6*t[68]+w7*t[69]+w8*t[70];
        }
    }
    #pragma unroll
    for (int k=0;k<4;++k){
        int p = threadIdx.x + 256*k;
        out[((size_t)(b*96+oc))*1024 + p] = acc[k];
        outb[((size_t)(b*1024+p))*96 + oc] = f2bf(acc[k]);
    }
}

// ---------------- MFMA implicit-GEMM 3x3 SAME conv on 32x32, IC=96.
template<int OCT, bool GATE>
__global__ __launch_bounds__(256,3) void k_convm(const u16* __restrict__ Xpb,
    const u16* __restrict__ Wt, const float* __restrict__ bias,
    float* __restrict__ out, int OC_real)
{
    constexpr int OCP = OCT*16;
    int b    = blockIdx.x >> 3;
    int pblk = blockIdx.x & 7;
    int tid  = threadIdx.x;
    int w = tid >> 6, lane = tid & 63;
    int cc = lane & 15, gg = lane >> 4;

    __shared__ __align__(16) u16 Ws[OCP][104];

    f32x4 acc[2][OCT];
    #pragma unroll
    for (int u=0;u<2;++u)
        #pragma unroll
        for (int t=0;t<OCT;++t) acc[u][t] = (f32x4){0.f,0.f,0.f,0.f};

    int base = pblk*128 + w*32;
    int ia = base >> 5;
    const u16* xb = Xpb + (size_t)b*1024*96;

    for (int tap=0; tap<9; ++tap){
        int dr = tap/3 - 1, dc = tap%3 - 1;
        __syncthreads();
        const u16* wt = Wt + (size_t)tap*OCP*96;
        for (int c = tid; c < OCP*12; c += 256){
            int oc = c/12, ico = (c%12)*8;
            *reinterpret_cast<short8*>(&Ws[oc][ico]) =
                *reinterpret_cast<const short8*>(wt + oc*96 + ico);
        }
        __syncthreads();

        int ii = ia + dr;
        int jj0 = cc + dc, jj1 = cc + 16 + dc;
        bool rv = ((unsigned)ii < 32u);
        bool v0 = rv && ((unsigned)jj0 < 32u);
        bool v1 = rv && ((unsigned)jj1 < 32u);
        const u16* ar0 = xb + (ptrdiff_t)(ii*32 + jj0)*96 + 8*gg;
        const u16* ar1 = xb + (ptrdiff_t)(ii*32 + jj1)*96 + 8*gg;

        #pragma unroll
        for (int ks=0; ks<3; ++ks){
            short8 a0 = {0,0,0,0,0,0,0,0};
            short8 a1 = {0,0,0,0,0,0,0,0};
            if (v0) a0 = *reinterpret_cast<const short8*>(ar0 + ks*32);
            if (v1) a1 = *reinterpret_cast<const short8*>(ar1 + ks*32);
            #pragma unroll
            for (int t=0; t<OCT; ++t){
                short8 bb = *reinterpret_cast<const short8*>(&Ws[t*16+cc][ks*32+8*gg]);
                acc[0][t] = __builtin_amdgcn_mfma_f32_16x16x32_bf16(a0, bb, acc[0][t], 0,0,0);
                acc[1][t] = __builtin_amdgcn_mfma_f32_16x16x32_bf16(a1, bb, acc[1][t], 0,0,0);
            }
        }
    }

    if constexpr (GATE){
        #pragma unroll
        for (int u=0;u<2;++u){
            int p0 = base + u*16 + gg*4;
            #pragma unroll
            for (int t=0;t<6;++t){
                int oca = t*16+cc;
                float ba = bias[oca], bbv = bias[oca+96];
                float* xp = out + ((size_t)(b*96 + oca))*1024 + p0;
                #pragma unroll
                for (int r=0;r<4;++r){
                    float va = acc[u][t][r]   + ba;
                    float vb = acc[u][t+6][r] + bbv;
                    xp[r] += va * sigm(vb);
                }
            }
        }
    } else {
        #pragma unroll
        for (int u=0;u<2;++u){
            int p0 = base + u*16 + gg*4;
            #pragma unroll
            for (int t=0;t<OCT;++t){
                int oc = t*16+cc;
                if (oc < OC_real){
                    float bv = bias[oc];
                    float* op = out + ((size_t)b*OC_real + oc)*1024 + p0;
                    #pragma unroll
                    for (int r=0;r<4;++r) op[r] = acc[u][t][r] + bv;
                }
            }
        }
    }
}

// ---------------- per-sample LayerNorm over 96*32*32; fp32 out optional, bf16 pixel-major out optional
__global__ __launch_bounds__(1024) void k_ln(const float* __restrict__ x,
    const float* __restrict__ gw, const float* __restrict__ bw,
    float* __restrict__ out, u16* __restrict__ outb)
{
    int b = blockIdx.x;
    const float* xb = x + (size_t)b*98304;
    float s=0.f, ss=0.f;
    for (int e=threadIdx.x; e<98304; e+=1024){ float v=xb[e]; s+=v; ss+=v*v; }
    #pragma unroll
    for (int o=32;o>0;o>>=1){ s += __shfl_down(s,o,64); ss += __shfl_down(ss,o,64); }
    __shared__ float rs[16], rss[16]; __shared__ float smu, srstd;
    int wid = threadIdx.x>>6;
    if ((threadIdx.x&63)==0){ rs[wid]=s; rss[wid]=ss; }
    __syncthreads();
    if (threadIdx.x==0){
        float S=0.f, SS=0.f;
        for (int i=0;i<16;++i){ S+=rs[i]; SS+=rss[i]; }
        float mu = S/98304.f;
        float var = SS/98304.f - mu*mu;
        smu = mu; srstd = rsqrtf(var + 1e-5f);
    }
    __syncthreads();
    float mu=smu, r=srstd;
    float* ob = out ? out + (size_t)b*98304 : nullptr;
    u16* obb = outb ? outb + (size_t)b*98304 : nullptr;
    for (int e=threadIdx.x; e<98304; e+=1024){
        float val = (xb[e]-mu)*r*gw[e] + bw[e];
        if (ob)  ob[e] = val;
        if (obb) obb[(size_t)(e & 1023)*96 + (e >> 10)] = f2bf(val);
    }
}

// ---------------- MFMA qkv GEMM: xlnb (B,1024,96) bf16 @ Wqkv^T (96,288) -> Q/K/V bf16
// block = (b, 128-pixel group), 4 waves x 32 pixels x 18 oc-tiles
__global__ __launch_bounds__(256,2) void k_qkvm(const u16* __restrict__ Xpb,
    const u16* __restrict__ Wt, const float* __restrict__ bias,
    u16* __restrict__ Qb, u16* __restrict__ Kbb, u16* __restrict__ Vtb)
{
    constexpr int OCT = 18, OCP = 288;
    int b    = blockIdx.x >> 3;
    int pblk = blockIdx.x & 7;
    int tid  = threadIdx.x;
    int w = tid >> 6, lane = tid & 63;
    int cc = lane & 15, gg = lane >> 4;

    __shared__ __align__(16) u16 Ws[OCP][104];
    for (int c = tid; c < OCP*12; c += 256){
        int oc = c/12, ico = (c%12)*8;
        *reinterpret_cast<short8*>(&Ws[oc][ico]) =
            *reinterpret_cast<const short8*>(Wt + oc*96 + ico);
    }

    f32x4 acc[2][OCT];
    #pragma unroll
    for (int u=0;u<2;++u)
        #pragma unroll
        for (int t=0;t<OCT;++t) acc[u][t] = (f32x4){0.f,0.f,0.f,0.f};

    int base = pblk*128 + w*32;
    const u16* xb = Xpb + ((size_t)b*1024 + base)*96;
    __syncthreads();

    #pragma unroll
    for (int ks=0; ks<3; ++ks){
        short8 a0 = *reinterpret_cast<const short8*>(xb + (size_t)cc*96      + ks*32 + 8*gg);
        short8 a1 = *reinterpret_cast<const short8*>(xb + (size_t)(cc+16)*96 + ks*32 + 8*gg);
        #pragma unroll
        for (int t=0; t<OCT; ++t){
            short8 bb = *reinterpret_cast<const short8*>(&Ws[t*16+cc][ks*32+8*gg]);
            acc[0][t] = __builtin_amdgcn_mfma_f32_16x16x32_bf16(a0, bb, acc[0][t], 0,0,0);
            acc[1][t] = __builtin_amdgcn_mfma_f32_16x16x32_bf16(a1, bb, acc[1][t], 0,0,0);
        }
    }

    #pragma unroll
    for (int u=0;u<2;++u){
        int p0 = base + u*16 + gg*4;
        #pragma unroll
        for (int t=0;t<OCT;++t){
            int n = t*16+cc;
            float bv = bias[n];
            #pragma unroll
            for (int r=0;r<4;++r){
                int p = p0 + r;
                u16 v = f2bf(acc[u][t][r] + bv);
                if (n < 96)       Qb[((size_t)(b*1024+p))*96 + n]        = v;
                else if (n < 192) Kbb[((size_t)(b*1024+p))*96 + (n-96)]  = v;
                else              Vtb[((size_t)((b*16+(p>>6))*96 + (n-192)))*64 + (p&63)] = v;
            }
        }
    }
}

// ---------------- MFMA proj GEMM + residual gate: Ob (B,1024,96) bf16 @ Wproj^T -> x2 fp32 ch-major
__global__ __launch_bounds__(256,3) void k_projm(const u16* __restrict__ Opb,
    const u16* __restrict__ Wt, const float* __restrict__ bias,
    const u16* __restrict__ xlnb, float* __restrict__ x2)
{
    constexpr int OCT = 12, OCP = 192;
    int b    = blockIdx.x >> 3;
    int pblk = blockIdx.x & 7;
    int tid  = threadIdx.x;
    int w = tid >> 6, lane = tid & 63;
    int cc = lane & 15, gg = lane >> 4;

    __shared__ __align__(16) u16 Ws[OCP][104];
    for (int c = tid; c < OCP*12; c += 256){
        int oc = c/12, ico = (c%12)*8;
        *reinterpret_cast<short8*>(&Ws[oc][ico]) =
            *reinterpret_cast<const short8*>(Wt + oc*96 + ico);
    }

    f32x4 acc[2][OCT];
    #pragma unroll
    for (int u=0;u<2;++u)
        #pragma unroll
        for (int t=0;t<OCT;++t) acc[u][t] = (f32x4){0.f,0.f,0.f,0.f};

    int base = pblk*128 + w*32;
    const u16* xb = Opb + ((size_t)b*1024 + base)*96;
    __syncthreads();

    #pragma unroll
    for (int ks=0; ks<3; ++ks){
        short8 a0 = *reinterpret_cast<const short8*>(xb + (size_t)cc*96      + ks*32 + 8*gg);
        short8 a1 = *reinterpret_cast<const short8*>(xb + (size_t)(cc+16)*96 + ks*32 + 8*gg);
        #pragma unroll
        for (int t=0; t<OCT; ++t){
            short8 bb = *reinterpret_cast<const short8*>(&Ws[t*16+cc][ks*32+8*gg]);
            acc[0][t] = __builtin_amdgcn_mfma_f32_16x16x32_bf16(a0, bb, acc[0][t], 0,0,0);
            acc[1][t] = __builtin_amdgcn_mfma_f32_16x16x32_bf16(a1, bb, acc[1][t], 0,0,0);
        }
    }

    const u16* resb = xlnb + (size_t)b*1024*96;
    #pragma unroll
    for (int u=0;u<2;++u){
        int p0 = base + u*16 + gg*4;
        #pragma unroll
        for (int t=0;t<6;++t){
            int oca = t*16+cc;
            float ba = bias[oca], bbv = bias[oca+96];
            float* xp = x2 + ((size_t)(b*96 + oca))*1024 + p0;
            #pragma unroll
            for (int r=0;r<4;++r){
                float ga = acc[u][t][r]   + ba;
                float gb = acc[u][t+6][r] + bbv;
                float res = bf2f(resb[(size_t)(p0+r)*96 + oca]);
                xp[r] = res + ga * sigm(gb);
            }
        }
    }
}

// ---------------- flash attention, bf16 MFMA 16x16x32; O written bf16 pixel-major
__global__ __launch_bounds__(256,4) void k_attn(const u16* __restrict__ Qb,
    const u16* __restrict__ Kbb, const u16* __restrict__ Vtb, u16* __restrict__ Ob)
{
    int b  = blockIdx.x >> 4;
    int q0 = (blockIdx.x & 15) * 64;
    int tid = threadIdx.x;
    int w  = tid >> 6;
    int lane = tid & 63;
    int cc = lane & 15;
    int gg = lane >> 4;

    __shared__ __align__(16) u16 Ks[64][104];
    __shared__ __align__(16) u16 Vs[96][72];
    __shared__ __align__(16) u16 Ps[4][16][72];

    short8 qf[3];
    const u16* qrow = Qb + ((size_t)(b*1024 + q0 + 16*w + cc))*96;
    #pragma unroll
    for (int ks=0; ks<3; ++ks)
        qf[ks] = *reinterpret_cast<const short8*>(qrow + ks*32 + 8*gg);

    f32x4 Oacc[6];
    #pragma unroll
    for (int ft=0; ft<6; ++ft) Oacc[ft] = (f32x4){0.f,0.f,0.f,0.f};
    float m_r[4] = {-1e30f,-1e30f,-1e30f,-1e30f};
    float l_r[4] = {0.f,0.f,0.f,0.f};

    const u16* Kbase = Kbb + (size_t)b*1024*96;
    const u16* Vbase = Vtb + (size_t)b*16*96*64;
    const float scale = 0.10206207262f;

    for (int jt=0; jt<16; ++jt){
        __syncthreads();
        const u16* kt = Kbase + (size_t)jt*64*96;
        #pragma unroll
        for (int ii=0; ii<3; ++ii){
            int i = tid + 256*ii;
            int key = i / 12, fo = (i % 12) * 8;
            *reinterpret_cast<short8*>(&Ks[key][fo]) =
                *reinterpret_cast<const short8*>(kt + key*96 + fo);
        }
        const u16* vt = Vbase + (size_t)jt*96*64;
        #pragma unroll
        for (int ii=0; ii<3; ++ii){
            int i = tid + 256*ii;
            int f = i >> 3, ko = (i & 7) * 8;
            *reinterpret_cast<short8*>(&Vs[f][ko]) =
                *reinterpret_cast<const short8*>(vt + f*64 + ko);
        }
        __syncthreads();

        f32x4 Sacc[4];
        #pragma unroll
        for (int t=0; t<4; ++t) Sacc[t] = (f32x4){0.f,0.f,0.f,0.f};
        #pragma unroll
        for (int ks=0; ks<3; ++ks){
            short8 a = qf[ks];
            #pragma unroll
            for (int t=0; t<4; ++t){
                short8 bb = *reinterpret_cast<const short8*>(&Ks[t*16+cc][ks*32+8*gg]);
                Sacc[t] = __builtin_amdgcn_mfma_f32_16x16x32_bf16(a, bb, Sacc[t], 0,0,0);
            }
        }
        float alpha[4];
        #pragma unroll
        for (int r=0; r<4; ++r){
            float s0 = Sacc[0][r]*scale, s1 = Sacc[1][r]*scale,
                  s2 = Sacc[2][r]*scale, s3 = Sacc[3][r]*scale;
            float mt = fmaxf(fmaxf(s0,s1), fmaxf(s2,s3));
            #pragma unroll
            for (int msk=1; msk<16; msk<<=1) mt = fmaxf(mt, __shfl_xor(mt, msk, 64));
            float mnew = fmaxf(m_r[r], mt);
            alpha[r] = __expf(m_r[r] - mnew);
            m_r[r] = mnew;
            float p0 = __expf(s0-mnew), p1 = __expf(s1-mnew),
                  p2 = __expf(s2-mnew), p3 = __expf(s3-mnew);
            Sacc[0][r]=p0; Sacc[1][r]=p1; Sacc[2][r]=p2; Sacc[3][r]=p3;
            float rs = p0+p1+p2+p3;
            #pragma unroll
            for (int msk=1; msk<16; msk<<=1) rs += __shfl_xor(rs, msk, 64);
            l_r[r] = l_r[r]*alpha[r] + rs;
        }
        #pragma unroll
        for (int ft=0; ft<6; ++ft){
            #pragma unroll
            for (int r=0; r<4; ++r) Oacc[ft][r] *= alpha[r];
        }
        #pragma unroll
        for (int t=0; t<4; ++t){
            #pragma unroll
            for (int r=0; r<4; ++r)
                Ps[w][4*gg + r][t*16 + cc] = f2bf(Sacc[t][r]);
        }
        #pragma unroll
        for (int kk=0; kk<2; ++kk){
            short8 pa = *reinterpret_cast<const short8*>(&Ps[w][cc][kk*32 + 8*gg]);
            #pragma unroll
            for (int ft=0; ft<6; ++ft){
                short8 vb = *reinterpret_cast<const short8*>(&Vs[ft*16+cc][kk*32+8*gg]);
                Oacc[ft] = __builtin_amdgcn_mfma_f32_16x16x32_bf16(pa, vb, Oacc[ft], 0,0,0);
            }
        }
    }

    float linv[4];
    #pragma unroll
    for (int r=0; r<4; ++r) linv[r] = 1.0f / l_r[r];
    #pragma unroll
    for (int ft=0; ft<6; ++ft){
        #pragma unroll
        for (int r=0; r<4; ++r)
            Ob[((size_t)(b*1024 + q0 + 16*w + 4*gg + r))*96 + ft*16 + cc] = f2bf(Oacc[ft][r]*linv[r]);
    }
}

// ---------------- copy incoming log_df_dz into output (atomicAdd target)
__global__ void k_initlog(const float* __restrict__ lin, float* __restrict__ lout)
{
    if (threadIdx.x < 64) lout[threadIdx.x] = lin[threadIdx.x];
}

// ---------------- mixture transform + merge + log-det
__global__ __launch_bounds__(256) void k_mix(const float* __restrict__ z,
    const float* __restrict__ params, const float* __restrict__ a_ls_p,
    const float* __restrict__ a_b_p, float* __restrict__ out_z, float* __restrict__ out_log)
{
    int b = blockIdx.x >> 2;
    int pix = (blockIdx.x & 3)*256 + threadIdx.x;
    int i = pix >> 5, j = pix & 31;
    float als = a_ls_p[0], abv = a_b_p[0];
    const float* pb = params + (size_t)b*156*1024;
    float logacc = 0.f;

    #pragma unroll
    for (int c=0;c<3;++c){
        int idx01 = ((b*3+c)*64 + 2*i)*64 + 2*j+1;
        int idx10 = ((b*3+c)*64 + 2*i+1)*64 + 2*j;
        out_z[idx01] = z[idx01];
        out_z[idx10] = z[idx10];
    }

    for (int c0=0;c0<6;++c0){
        float z0v = (c0<3) ? z[((b*3+c0)*64 + 2*i)*64 + 2*j]
                           : z[((b*3+(c0-3))*64 + 2*i+1)*64 + 2*j+1];
        float a_raw = pb[(c0)*1024 + pix];
        float bco   = pb[(6+c0)*1024 + pix];
        float lp[8], mu[8], sv[8];
        float m1 = -1e30f;
        #pragma unroll
        for (int k=0;k<8;++k){
            lp[k] = pb[(12 + k*6 + c0)*1024 + pix];
            mu[k] = pb[(60 + k*6 + c0)*1024 + pix];
            sv[k] = pb[(108 + k*6 + c0)*1024 + pix];
            m1 = fmaxf(m1, lp[k]);
        }
        float se = 0.f;
        #pragma unroll
        for (int k=0;k<8;++k) se += __expf(lp[k]-m1);
        float lse = m1 + __logf(se);
        float xm = 0.f, mt = -1e30f;
        float t[8];
        #pragma unroll
        for (int k=0;k<8;++k){
            float lpn = lp[k] - lse;
            float u = (z0v - mu[k]) * __expf(-sv[k]);
            float au = fabsf(u);
            xm += __expf(lpn) * (1.f/(1.f+__expf(-u)));
            float lss = -(au + 2.f*log1pf(__expf(-au)));
            float tk = lpn - sv[k] + lss;
            t[k] = tk; mt = fmaxf(mt, tk);
        }
        float se2 = 0.f;
        #pragma unroll
        for (int k=0;k<8;++k) se2 += __expf(t[k]-mt);
        logacc += mt + __logf(se2);
        xm = fminf(fmaxf(xm, 1e-6f), 1.f-1e-6f);
        float lx = __logf(xm), l1x = log1pf(-xm);
        logacc += -lx - l1x;
        float aa = tanhf(a_raw)*als + abv;
        float z0n = (lx - l1x)*__expf(aa) + bco;
        logacc += aa;
        int oidx = (c0<3) ? ((b*3+c0)*64 + 2*i)*64 + 2*j
                          : ((b*3+(c0-3))*64 + 2*i+1)*64 + 2*j+1;
        out_z[oidx] = z0n;
    }

    #pragma unroll
    for (int o=32;o>0;o>>=1) logacc += __shfl_down(logacc, o, 64);
    __shared__ float part[4];
    if ((threadIdx.x&63)==0) part[threadIdx.x>>6] = logacc;
    __syncthreads();
    if (threadIdx.x==0){
        atomicAdd(out_log + b, part[0]+part[1]+part[2]+part[3]);
    }
}

extern "C" void kernel_launch(void* const* d_in, const int* in_sizes, int n_in,
                              void* d_out, int out_size, void* d_ws, size_t ws_size,
                              hipStream_t stream)
{
    const float* z     = (const float*)d_in[0];
    const float* logdf = (const float*)d_in[1];
    const float* c1w   = (const float*)d_in[2];
    const float* c1b   = (const float*)d_in[3];
    const float* gw    = (const float*)d_in[4];
    const float* gcb   = (const float*)d_in[5];
    const float* ln1g  = (const float*)d_in[6];
    const float* ln1b  = (const float*)d_in[7];
    const float* qkvw  = (const float*)d_in[8];
    const float* qkvb  = (const float*)d_in[9];
    const float* pw    = (const float*)d_in[10];
    const float* pbb   = (const float*)d_in[11];
    const float* ln2g  = (const float*)d_in[12];
    const float* ln2b  = (const float*)d_in[13];
    const float* c2w   = (const float*)d_in[14];
    const float* c2b   = (const float*)d_in[15];
    const float* als   = (const float*)d_in[16];
    const float* ab    = (const float*)d_in[17];

    float* out_z   = (float*)d_out;
    float* out_log = out_z + 786432;

    // workspace (float units), peak 25,340,928 floats = 101.4 MB
    float* ws     = (float*)d_ws;
    float* x1     = ws;                        // (B,96,1024) fp32; conv1 -> gated in-place [0, 6291456)
    u16*   x1b    = (u16*)(ws + 6291456);      // (B,1024,96) bf16 (gconv input)  [6291456, 9437184)
    u16*   xlnb   = (u16*)(ws + 9437184);      // (B,1024,96) bf16 LN1 out        [9437184, 12582912)
    u16*   Qb     = x1b;                       // reuse (x1b dead after gconv)
    u16*   Kbb    = (u16*)(ws + 12582912);     // [12582912, 15728640)
    u16*   Vtb    = (u16*)(ws + 15728640);     // [15728640, 18874368)
    u16*   Ob     = (u16*)ws;                  // (B,1024,96) bf16 attn out (x1 dead after LN1) [0, 3145728)
    u16*   xln2b  = (u16*)(ws + 3145728);      // (B,1024,96) bf16 LN2 out [3145728, 6291456)
    float* x2     = ws + 18874368;             // (B,96,1024) fp32 proj out [18874368, 25165824)
    float* params = ws + 6291456;              // (B,156,1024) [6291456, 16515072) (Q/K/V/xlnb dead)
    u16*   Wg     = (u16*)(ws + 25165824);     // [9][192][96]
    u16*   W2     = (u16*)(ws + 25248768);     // [9][160][96]
    u16*   Wqkv   = (u16*)(ws + 25317888);     // [288][96]
    u16*   Wproj  = (u16*)(ws + 25331712);     // [192][96]

    k_wrep   <<<648 , 256, 0, stream>>>(gw,  Wg, 192, 192);
    k_wrep   <<<540 , 256, 0, stream>>>(c2w, W2, 156, 160);
    k_wrepm  <<<108 , 256, 0, stream>>>(qkvw, Wqkv, 288*96);
    k_wrepm  <<<72  , 256, 0, stream>>>(pw, Wproj, 192*96);
    k_conv1  <<<6144, 256, 0, stream>>>(z, c1w, c1b, x1, x1b);
    k_convm<12,true> <<<512, 256, 0, stream>>>(x1b, Wg, gcb, x1, 192);
    k_ln     <<<64  ,1024, 0, stream>>>(x1, ln1g, ln1b, nullptr, xlnb);
    k_qkvm   <<<512 , 256, 0, stream>>>(xlnb, Wqkv, qkvb, Qb, Kbb, Vtb);
    k_attn   <<<1024, 256, 0, stream>>>(Qb, Kbb, Vtb, Ob);
    k_projm  <<<512 , 256, 0, stream>>>(Ob, Wproj, pbb, xlnb, x2);
    k_ln     <<<64  ,1024, 0, stream>>>(x2, ln2g, ln2b, nullptr, xln2b);
    k_convm<10,false><<<512, 256, 0, stream>>>(xln2b, W2, c2b, params, 156);
    k_initlog<<<1   ,  64, 0, stream>>>(logdf, out_log);
    k_mix    <<<256 , 256, 0, stream>>>(z, params, als, ab, out_z, out_log);
}

// Round 5
// 399.507 us; speedup vs baseline: 12.3120x; 1.7268x over previous
//
#include <hip/hip_runtime.h>
#include <cstdint>
#include <cstddef>

// Problem constants: B=64, C=3, H=W=64, F=96, K=8, h=w=32, C0=6, P=h*w=1024
// params channels: a[0:6) b[6:12) logpi[12:60) mu[60:108) s[108:156)

typedef unsigned short u16;
typedef __attribute__((ext_vector_type(8))) short short8;
typedef __attribute__((ext_vector_type(4))) float f32x4;

__device__ __forceinline__ float sigm(float x){ return 1.0f/(1.0f+__expf(-x)); }

__device__ __forceinline__ u16 f2bf(float f){
    unsigned int u = __float_as_uint(f);
    u += 0x7fffu + ((u >> 16) & 1u);
    return (u16)(u >> 16);
}
__device__ __forceinline__ float bf2f(u16 v){
    unsigned int u = ((unsigned int)v) << 16;
    return __uint_as_float(u);
}

// ---------------- weight repack: W (OC,96,3,3) fp32 -> Wt[tap][oc][ic] bf16, oc padded to OCP
__global__ __launch_bounds__(256) void k_wrep(const float* __restrict__ w,
    u16* __restrict__ wt, int OCR, int OCP)
{
    int idx = blockIdx.x*256 + threadIdx.x;
    if (idx >= 9*OCP*96) return;
    int tap = idx / (OCP*96);
    int rem = idx - tap*OCP*96;
    int oc = rem / 96, ic = rem % 96;
    wt[idx] = (oc < OCR) ? f2bf(w[(size_t)(oc*96+ic)*9 + tap]) : (u16)0;
}

// ---------------- matrix repack: W (N,96) fp32 -> bf16 (N,96)
__global__ __launch_bounds__(256) void k_wrepm(const float* __restrict__ w,
    u16* __restrict__ wt, int n)
{
    int idx = blockIdx.x*256 + threadIdx.x;
    if (idx < n) wt[idx] = f2bf(w[idx]);
}

// ---------------- LN weight transpose: (96,1024) fp32 -> (1024,96) fp32
__global__ __launch_bounds__(256) void k_wrepln(const float* __restrict__ src,
    float* __restrict__ dst)
{
    int idx = blockIdx.x*256 + threadIdx.x;
    if (idx < 98304){
        int c = idx >> 10, p = idx & 1023;
        dst[p*96 + c] = src[idx];
    }
}

// ---------------- conv1: z(B,3,64,64) checker-gathered as z1(B,6,32,32) -> bf16 pixel-major (B,1024,96)
// block = (b, 128-pixel group = 4 image rows). Weights + input tile in LDS; thread = (pixel, 48-oc half).
__global__ __launch_bounds__(256) void k_conv1(const float* __restrict__ z,
        const float* __restrict__ w, const float* __restrict__ bias,
        u16* __restrict__ outb)
{
    int b  = blockIdx.x >> 3;
    int pg = blockIdx.x & 7;
    int r0 = pg*4;
    int tid = threadIdx.x;

    __shared__ float wsm[96][56];      // [oc][k], k=c*9+dr*3+dc (54 used)
    __shared__ float tin[6][6][34];    // [ch][row r0-1..r0+4][col -1..32]

    for (int idx = tid; idx < 96*54; idx += 256){
        int oc = idx/54, k = idx%54;
        wsm[oc][k] = w[oc*54 + k];
    }
    for (int idx = tid; idx < 6*6*34; idx += 256){
        int c = idx/204, rem = idx%204;
        int rr = rem/34, q = rem%34;
        int ii = r0 - 1 + rr, jj = q - 1;
        float v = 0.f;
        if ((unsigned)ii < 32u && (unsigned)jj < 32u){
            if (c < 3) v = z[((b*3+c)*64 + 2*ii)*64 + (2*jj+1)];        // p01
            else       v = z[((b*3+(c-3))*64 + (2*ii+1))*64 + 2*jj];    // p10
        }
        tin[c][rr][q] = v;
    }
    __syncthreads();

    int px = tid >> 1, half = tid & 1;
    int lr = (px >> 5) + 1;        // tile row of this pixel
    int col = (px & 31) + 1;       // tile col

    float in[54];
    #pragma unroll
    for (int c=0;c<6;++c)
        #pragma unroll
        for (int dr=0;dr<3;++dr)
            #pragma unroll
            for (int dc=0;dc<3;++dc)
                in[c*9+dr*3+dc] = tin[c][lr-1+dr][col-1+dc];

    int oc0 = half*48;
    u16* op = outb + ((size_t)(b*1024) + pg*128 + px)*96 + oc0;
    for (int og=0; og<12; ++og){
        float a0 = bias[oc0+og*4+0], a1 = bias[oc0+og*4+1],
              a2 = bias[oc0+og*4+2], a3 = bias[oc0+og*4+3];
        const float* w0 = wsm[oc0+og*4+0];
        const float* w1 = wsm[oc0+og*4+1];
        const float* w2 = wsm[oc0+og*4+2];
        const float* w3 = wsm[oc0+og*4+3];
        #pragma unroll
        for (int k=0;k<54;++k){
            float iv = in[k];
            a0 += iv*w0[k]; a1 += iv*w1[k]; a2 += iv*w2[k]; a3 += iv*w3[k];
        }
        op[og*4+0] = f2bf(a0); op[og*4+1] = f2bf(a1);
        op[og*4+2] = f2bf(a2); op[og*4+3] = f2bf(a3);
    }
}

// ---------------- gated conv (MFMA implicit GEMM, OC=192) + residual gate + LN1 partial stats
// out bf16 pixel-major; partials[(b*8+pblk)*2 + {0,1}] = block {sum, sumsq}
__global__ __launch_bounds__(256,3) void k_gconv(const u16* __restrict__ Xpb,
    const u16* __restrict__ Wt, const float* __restrict__ bias,
    u16* __restrict__ outb, float* __restrict__ partials)
{
    constexpr int OCT = 12, OCP = 192;
    int b    = blockIdx.x >> 3;
    int pblk = blockIdx.x & 7;
    int tid  = threadIdx.x;
    int w = tid >> 6, lane = tid & 63;
    int cc = lane & 15, gg = lane >> 4;

    __shared__ __align__(16) u16 Ws[OCP][104];
    __shared__ float red[8];

    f32x4 acc[2][OCT];
    #pragma unroll
    for (int u=0;u<2;++u)
        #pragma unroll
        for (int t=0;t<OCT;++t) acc[u][t] = (f32x4){0.f,0.f,0.f,0.f};

    int base = pblk*128 + w*32;
    int ia = base >> 5;
    const u16* xb = Xpb + (size_t)b*1024*96;

    for (int tap=0; tap<9; ++tap){
        int dr = tap/3 - 1, dc = tap%3 - 1;
        __syncthreads();
        const u16* wt = Wt + (size_t)tap*OCP*96;
        for (int c = tid; c < OCP*12; c += 256){
            int oc = c/12, ico = (c%12)*8;
            *reinterpret_cast<short8*>(&Ws[oc][ico]) =
                *reinterpret_cast<const short8*>(wt + oc*96 + ico);
        }
        __syncthreads();

        int ii = ia + dr;
        int jj0 = cc + dc, jj1 = cc + 16 + dc;
        bool rv = ((unsigned)ii < 32u);
        bool v0 = rv && ((unsigned)jj0 < 32u);
        bool v1 = rv && ((unsigned)jj1 < 32u);
        const u16* ar0 = xb + (ptrdiff_t)(ii*32 + jj0)*96 + 8*gg;
        const u16* ar1 = xb + (ptrdiff_t)(ii*32 + jj1)*96 + 8*gg;

        #pragma unroll
        for (int ks=0; ks<3; ++ks){
            short8 a0 = {0,0,0,0,0,0,0,0};
            short8 a1 = {0,0,0,0,0,0,0,0};
            if (v0) a0 = *reinterpret_cast<const short8*>(ar0 + ks*32);
            if (v1) a1 = *reinterpret_cast<const short8*>(ar1 + ks*32);
            #pragma unroll
            for (int t=0; t<OCT; ++t){
                short8 bb = *reinterpret_cast<const short8*>(&Ws[t*16+cc][ks*32+8*gg]);
                acc[0][t] = __builtin_amdgcn_mfma_f32_16x16x32_bf16(a0, bb, acc[0][t], 0,0,0);
                acc[1][t] = __builtin_amdgcn_mfma_f32_16x16x32_bf16(a1, bb, acc[1][t], 0,0,0);
            }
        }
    }

    float s = 0.f, ssq = 0.f;
    #pragma unroll
    for (int u=0;u<2;++u){
        int p0 = base + u*16 + gg*4;
        #pragma unroll
        for (int t=0;t<6;++t){
            int oca = t*16+cc;
            float ba = bias[oca], bbv = bias[oca+96];
            #pragma unroll
            for (int r=0;r<4;++r){
                float res = bf2f(Xpb[((size_t)b*1024 + p0+r)*96 + oca]);
                float va = acc[u][t][r]   + ba;
                float vb = acc[u][t+6][r] + bbv;
                float v = res + va*sigm(vb);
                outb[((size_t)b*1024 + p0+r)*96 + oca] = f2bf(v);
                s += v; ssq += v*v;
            }
        }
    }
    #pragma unroll
    for (int o=32;o>0;o>>=1){ s += __shfl_down(s,o,64); ssq += __shfl_down(ssq,o,64); }
    if (lane==0){ red[w]=s; red[4+w]=ssq; }
    __syncthreads();
    if (tid==0){
        partials[(b*8+pblk)*2+0] = red[0]+red[1]+red[2]+red[3];
        partials[(b*8+pblk)*2+1] = red[4]+red[5]+red[6]+red[7];
    }
}

// ---------------- fold 8 partials/b -> (mu, rstd)
__global__ void k_stats(const float* __restrict__ partials, float* __restrict__ stats)
{
    int b = threadIdx.x;
    if (b < 64){
        float s=0.f, ss=0.f;
        for (int i=0;i<8;++i){ s += partials[(b*8+i)*2]; ss += partials[(b*8+i)*2+1]; }
        float mu = s/98304.f;
        float var = ss/98304.f - mu*mu;
        stats[b*2]   = mu;
        stats[b*2+1] = rsqrtf(var + 1e-5f);
    }
}

// ---------------- LN apply, flat coalesced: x bf16 [b][98304] -> out bf16, affine from transposed weights
__global__ __launch_bounds__(256) void k_lne(const u16* __restrict__ xb,
    const float* __restrict__ gt, const float* __restrict__ bt,
    const float* __restrict__ stats, u16* __restrict__ out)
{
    int b = blockIdx.x / 48, rem = blockIdx.x % 48;
    int e8 = rem*256 + threadIdx.x;          // 0..12287
    size_t base = (size_t)b*98304 + (size_t)e8*8;
    float mu = stats[b*2], r = stats[b*2+1];
    short8 x8 = *reinterpret_cast<const short8*>(xb + base);
    const float* gp = gt + e8*8;
    const float* bp = bt + e8*8;
    short8 o8;
    #pragma unroll
    for (int i=0;i<8;++i)
        o8[i] = (short)f2bf((bf2f((u16)x8[i]) - mu)*r*gp[i] + bp[i]);
    *reinterpret_cast<short8*>(out + base) = o8;
}

// ---------------- conv2 (MFMA implicit GEMM, OC=156 padded 160) -> params fp32 ch-major
__global__ __launch_bounds__(256,3) void k_conv2m(const u16* __restrict__ Xpb,
    const u16* __restrict__ Wt, const float* __restrict__ bias,
    float* __restrict__ out)
{
    constexpr int OCT = 10, OCP = 160;
    int b    = blockIdx.x >> 3;
    int pblk = blockIdx.x & 7;
    int tid  = threadIdx.x;
    int w = tid >> 6, lane = tid & 63;
    int cc = lane & 15, gg = lane >> 4;

    __shared__ __align__(16) u16 Ws[OCP][104];

    f32x4 acc[2][OCT];
    #pragma unroll
    for (int u=0;u<2;++u)
        #pragma unroll
        for (int t=0;t<OCT;++t) acc[u][t] = (f32x4){0.f,0.f,0.f,0.f};

    int base = pblk*128 + w*32;
    int ia = base >> 5;
    const u16* xb = Xpb + (size_t)b*1024*96;

    for (int tap=0; tap<9; ++tap){
        int dr = tap/3 - 1, dc = tap%3 - 1;
        __syncthreads();
        const u16* wt = Wt + (size_t)tap*OCP*96;
        for (int c = tid; c < OCP*12; c += 256){
            int oc = c/12, ico = (c%12)*8;
            *reinterpret_cast<short8*>(&Ws[oc][ico]) =
                *reinterpret_cast<const short8*>(wt + oc*96 + ico);
        }
        __syncthreads();

        int ii = ia + dr;
        int jj0 = cc + dc, jj1 = cc + 16 + dc;
        bool rv = ((unsigned)ii < 32u);
        bool v0 = rv && ((unsigned)jj0 < 32u);
        bool v1 = rv && ((unsigned)jj1 < 32u);
        const u16* ar0 = xb + (ptrdiff_t)(ii*32 + jj0)*96 + 8*gg;
        const u16* ar1 = xb + (ptrdiff_t)(ii*32 + jj1)*96 + 8*gg;

        #pragma unroll
        for (int ks=0; ks<3; ++ks){
            short8 a0 = {0,0,0,0,0,0,0,0};
            short8 a1 = {0,0,0,0,0,0,0,0};
            if (v0) a0 = *reinterpret_cast<const short8*>(ar0 + ks*32);
            if (v1) a1 = *reinterpret_cast<const short8*>(ar1 + ks*32);
            #pragma unroll
            for (int t=0; t<OCT; ++t){
                short8 bb = *reinterpret_cast<const short8*>(&Ws[t*16+cc][ks*32+8*gg]);
                acc[0][t] = __builtin_amdgcn_mfma_f32_16x16x32_bf16(a0, bb, acc[0][t], 0,0,0);
                acc[1][t] = __builtin_amdgcn_mfma_f32_16x16x32_bf16(a1, bb, acc[1][t], 0,0,0);
            }
        }
    }

    #pragma unroll
    for (int u=0;u<2;++u){
        int p0 = base + u*16 + gg*4;
        #pragma unroll
        for (int t=0;t<OCT;++t){
            int oc = t*16+cc;
            if (oc < 156){
                float bv = bias[oc];
                float* op = out + ((size_t)b*156 + oc)*1024 + p0;
                #pragma unroll
                for (int r=0;r<4;++r) op[r] = acc[u][t][r] + bv;
            }
        }
    }
}

// ---------------- MFMA qkv GEMM: xlnb (B,1024,96) bf16 @ Wqkv^T (96,288) -> Q/K/V bf16
__global__ __launch_bounds__(256,2) void k_qkvm(const u16* __restrict__ Xpb,
    const u16* __restrict__ Wt, const float* __restrict__ bias,
    u16* __restrict__ Qb, u16* __restrict__ Kbb, u16* __restrict__ Vtb)
{
    constexpr int OCT = 18, OCP = 288;
    int b    = blockIdx.x >> 3;
    int pblk = blockIdx.x & 7;
    int tid  = threadIdx.x;
    int w = tid >> 6, lane = tid & 63;
    int cc = lane & 15, gg = lane >> 4;

    __shared__ __align__(16) u16 Ws[OCP][104];
    for (int c = tid; c < OCP*12; c += 256){
        int oc = c/12, ico = (c%12)*8;
        *reinterpret_cast<short8*>(&Ws[oc][ico]) =
            *reinterpret_cast<const short8*>(Wt + oc*96 + ico);
    }

    f32x4 acc[2][OCT];
    #pragma unroll
    for (int u=0;u<2;++u)
        #pragma unroll
        for (int t=0;t<OCT;++t) acc[u][t] = (f32x4){0.f,0.f,0.f,0.f};

    int base = pblk*128 + w*32;
    const u16* xb = Xpb + ((size_t)b*1024 + base)*96;
    __syncthreads();

    #pragma unroll
    for (int ks=0; ks<3; ++ks){
        short8 a0 = *reinterpret_cast<const short8*>(xb + (size_t)cc*96      + ks*32 + 8*gg);
        short8 a1 = *reinterpret_cast<const short8*>(xb + (size_t)(cc+16)*96 + ks*32 + 8*gg);
        #pragma unroll
        for (int t=0; t<OCT; ++t){
            short8 bb = *reinterpret_cast<const short8*>(&Ws[t*16+cc][ks*32+8*gg]);
            acc[0][t] = __builtin_amdgcn_mfma_f32_16x16x32_bf16(a0, bb, acc[0][t], 0,0,0);
            acc[1][t] = __builtin_amdgcn_mfma_f32_16x16x32_bf16(a1, bb, acc[1][t], 0,0,0);
        }
    }

    #pragma unroll
    for (int u=0;u<2;++u){
        int p0 = base + u*16 + gg*4;
        #pragma unroll
        for (int t=0;t<OCT;++t){
            int n = t*16+cc;
            float bv = bias[n];
            #pragma unroll
            for (int r=0;r<4;++r){
                int p = p0 + r;
                u16 v = f2bf(acc[u][t][r] + bv);
                if (n < 96)       Qb[((size_t)(b*1024+p))*96 + n]        = v;
                else if (n < 192) Kbb[((size_t)(b*1024+p))*96 + (n-96)]  = v;
                else              Vtb[((size_t)((b*16+(p>>6))*96 + (n-192)))*64 + (p&63)] = v;
            }
        }
    }
}

// ---------------- MFMA proj GEMM + residual gate + LN2 partial stats; out bf16 pixel-major
__global__ __launch_bounds__(256,3) void k_projm(const u16* __restrict__ Opb,
    const u16* __restrict__ Wt, const float* __restrict__ bias,
    const u16* __restrict__ xlnb, u16* __restrict__ outb, float* __restrict__ partials)
{
    constexpr int OCT = 12, OCP = 192;
    int b    = blockIdx.x >> 3;
    int pblk = blockIdx.x & 7;
    int tid  = threadIdx.x;
    int w = tid >> 6, lane = tid & 63;
    int cc = lane & 15, gg = lane >> 4;

    __shared__ __align__(16) u16 Ws[OCP][104];
    __shared__ float red[8];
    for (int c = tid; c < OCP*12; c += 256){
        int oc = c/12, ico = (c%12)*8;
        *reinterpret_cast<short8*>(&Ws[oc][ico]) =
            *reinterpret_cast<const short8*>(Wt + oc*96 + ico);
    }

    f32x4 acc[2][OCT];
    #pragma unroll
    for (int u=0;u<2;++u)
        #pragma unroll
        for (int t=0;t<OCT;++t) acc[u][t] = (f32x4){0.f,0.f,0.f,0.f};

    int base = pblk*128 + w*32;
    const u16* xb = Opb + ((size_t)b*1024 + base)*96;
    __syncthreads();

    #pragma unroll
    for (int ks=0; ks<3; ++ks){
        short8 a0 = *reinterpret_cast<const short8*>(xb + (size_t)cc*96      + ks*32 + 8*gg);
        short8 a1 = *reinterpret_cast<const short8*>(xb + (size_t)(cc+16)*96 + ks*32 + 8*gg);
        #pragma unroll
        for (int t=0; t<OCT; ++t){
            short8 bb = *reinterpret_cast<const short8*>(&Ws[t*16+cc][ks*32+8*gg]);
            acc[0][t] = __builtin_amdgcn_mfma_f32_16x16x32_bf16(a0, bb, acc[0][t], 0,0,0);
            acc[1][t] = __builtin_amdgcn_mfma_f32_16x16x32_bf16(a1, bb, acc[1][t], 0,0,0);
        }
    }

    const u16* resb = xlnb + (size_t)b*1024*96;
    float s = 0.f, ssq = 0.f;
    #pragma unroll
    for (int u=0;u<2;++u){
        int p0 = base + u*16 + gg*4;
        #pragma unroll
        for (int t=0;t<6;++t){
            int oca = t*16+cc;
            float ba = bias[oca], bbv = bias[oca+96];
            #pragma unroll
            for (int r=0;r<4;++r){
                float ga = acc[u][t][r]   + ba;
                float gb = acc[u][t+6][r] + bbv;
                float res = bf2f(resb[(size_t)(p0+r)*96 + oca]);
                float v = res + ga * sigm(gb);
                outb[((size_t)b*1024 + p0+r)*96 + oca] = f2bf(v);
                s += v; ssq += v*v;
            }
        }
    }
    #pragma unroll
    for (int o=32;o>0;o>>=1){ s += __shfl_down(s,o,64); ssq += __shfl_down(ssq,o,64); }
    if (lane==0){ red[w]=s; red[4+w]=ssq; }
    __syncthreads();
    if (tid==0){
        partials[(b*8+pblk)*2+0] = red[0]+red[1]+red[2]+red[3];
        partials[(b*8+pblk)*2+1] = red[4]+red[5]+red[6]+red[7];
    }
}

// ---------------- flash attention, bf16 MFMA 16x16x32; O written bf16 pixel-major
__global__ __launch_bounds__(256,4) void k_attn(const u16* __restrict__ Qb,
    const u16* __restrict__ Kbb, const u16* __restrict__ Vtb, u16* __restrict__ Ob)
{
    int b  = blockIdx.x >> 4;
    int q0 = (blockIdx.x & 15) * 64;
    int tid = threadIdx.x;
    int w  = tid >> 6;
    int lane = tid & 63;
    int cc = lane & 15;
    int gg = lane >> 4;

    __shared__ __align__(16) u16 Ks[64][104];
    __shared__ __align__(16) u16 Vs[96][72];
    __shared__ __align__(16) u16 Ps[4][16][72];

    short8 qf[3];
    const u16* qrow = Qb + ((size_t)(b*1024 + q0 + 16*w + cc))*96;
    #pragma unroll
    for (int ks=0; ks<3; ++ks)
        qf[ks] = *reinterpret_cast<const short8*>(qrow + ks*32 + 8*gg);

    f32x4 Oacc[6];
    #pragma unroll
    for (int ft=0; ft<6; ++ft) Oacc[ft] = (f32x4){0.f,0.f,0.f,0.f};
    float m_r[4] = {-1e30f,-1e30f,-1e30f,-1e30f};
    float l_r[4] = {0.f,0.f,0.f,0.f};

    const u16* Kbase = Kbb + (size_t)b*1024*96;
    const u16* Vbase = Vtb + (size_t)b*16*96*64;
    const float scale = 0.10206207262f;

    for (int jt=0; jt<16; ++jt){
        __syncthreads();
        const u16* kt = Kbase + (size_t)jt*64*96;
        #pragma unroll
        for (int ii=0; ii<3; ++ii){
            int i = tid + 256*ii;
            int key = i / 12, fo = (i % 12) * 8;
            *reinterpret_cast<short8*>(&Ks[key][fo]) =
                *reinterpret_cast<const short8*>(kt + key*96 + fo);
        }
        const u16* vt = Vbase + (size_t)jt*96*64;
        #pragma unroll
        for (int ii=0; ii<3; ++ii){
            int i = tid + 256*ii;
            int f = i >> 3, ko = (i & 7) * 8;
            *reinterpret_cast<short8*>(&Vs[f][ko]) =
                *reinterpret_cast<const short8*>(vt + f*64 + ko);
        }
        __syncthreads();

        f32x4 Sacc[4];
        #pragma unroll
        for (int t=0; t<4; ++t) Sacc[t] = (f32x4){0.f,0.f,0.f,0.f};
        #pragma unroll
        for (int ks=0; ks<3; ++ks){
            short8 a = qf[ks];
            #pragma unroll
            for (int t=0; t<4; ++t){
                short8 bb = *reinterpret_cast<const short8*>(&Ks[t*16+cc][ks*32+8*gg]);
                Sacc[t] = __builtin_amdgcn_mfma_f32_16x16x32_bf16(a, bb, Sacc[t], 0,0,0);
            }
        }
        float alpha[4];
        #pragma unroll
        for (int r=0; r<4; ++r){
            float s0 = Sacc[0][r]*scale, s1 = Sacc[1][r]*scale,
                  s2 = Sacc[2][r]*scale, s3 = Sacc[3][r]*scale;
            float mt = fmaxf(fmaxf(s0,s1), fmaxf(s2,s3));
            #pragma unroll
            for (int msk=1; msk<16; msk<<=1) mt = fmaxf(mt, __shfl_xor(mt, msk, 64));
            float mnew = fmaxf(m_r[r], mt);
            alpha[r] = __expf(m_r[r] - mnew);
            m_r[r] = mnew;
            float p0 = __expf(s0-mnew), p1 = __expf(s1-mnew),
                  p2 = __expf(s2-mnew), p3 = __expf(s3-mnew);
            Sacc[0][r]=p0; Sacc[1][r]=p1; Sacc[2][r]=p2; Sacc[3][r]=p3;
            float rs = p0+p1+p2+p3;
            #pragma unroll
            for (int msk=1; msk<16; msk<<=1) rs += __shfl_xor(rs, msk, 64);
            l_r[r] = l_r[r]*alpha[r] + rs;
        }
        #pragma unroll
        for (int ft=0; ft<6; ++ft){
            #pragma unroll
            for (int r=0; r<4; ++r) Oacc[ft][r] *= alpha[r];
        }
        #pragma unroll
        for (int t=0; t<4; ++t){
            #pragma unroll
            for (int r=0; r<4; ++r)
                Ps[w][4*gg + r][t*16 + cc] = f2bf(Sacc[t][r]);
        }
        #pragma unroll
        for (int kk=0; kk<2; ++kk){
            short8 pa = *reinterpret_cast<const short8*>(&Ps[w][cc][kk*32 + 8*gg]);
            #pragma unroll
            for (int ft=0; ft<6; ++ft){
                short8 vb = *reinterpret_cast<const short8*>(&Vs[ft*16+cc][kk*32+8*gg]);
                Oacc[ft] = __builtin_amdgcn_mfma_f32_16x16x32_bf16(pa, vb, Oacc[ft], 0,0,0);
            }
        }
    }

    float linv[4];
    #pragma unroll
    for (int r=0; r<4; ++r) linv[r] = 1.0f / l_r[r];
    #pragma unroll
    for (int ft=0; ft<6; ++ft){
        #pragma unroll
        for (int r=0; r<4; ++r)
            Ob[((size_t)(b*1024 + q0 + 16*w + 4*gg + r))*96 + ft*16 + cc] = f2bf(Oacc[ft][r]*linv[r]);
    }
}

// ---------------- copy incoming log_df_dz into output (atomicAdd target)
__global__ void k_initlog(const float* __restrict__ lin, float* __restrict__ lout)
{
    if (threadIdx.x < 64) lout[threadIdx.x] = lin[threadIdx.x];
}

// ---------------- mixture transform + merge + log-det
__global__ __launch_bounds__(256) void k_mix(const float* __restrict__ z,
    const float* __restrict__ params, const float* __restrict__ a_ls_p,
    const float* __restrict__ a_b_p, float* __restrict__ out_z, float* __restrict__ out_log)
{
    int b = blockIdx.x >> 2;
    int pix = (blockIdx.x & 3)*256 + threadIdx.x;
    int i = pix >> 5, j = pix & 31;
    float als = a_ls_p[0], abv = a_b_p[0];
    const float* pb = params + (size_t)b*156*1024;
    float logacc = 0.f;

    #pragma unroll
    for (int c=0;c<3;++c){
        int idx01 = ((b*3+c)*64 + 2*i)*64 + 2*j+1;
        int idx10 = ((b*3+c)*64 + 2*i+1)*64 + 2*j;
        out_z[idx01] = z[idx01];
        out_z[idx10] = z[idx10];
    }

    for (int c0=0;c0<6;++c0){
        float z0v = (c0<3) ? z[((b*3+c0)*64 + 2*i)*64 + 2*j]
                           : z[((b*3+(c0-3))*64 + 2*i+1)*64 + 2*j+1];
        float a_raw = pb[(c0)*1024 + pix];
        float bco   = pb[(6+c0)*1024 + pix];
        float lp[8], mu[8], sv[8];
        float m1 = -1e30f;
        #pragma unroll
        for (int k=0;k<8;++k){
            lp[k] = pb[(12 + k*6 + c0)*1024 + pix];
            mu[k] = pb[(60 + k*6 + c0)*1024 + pix];
            sv[k] = pb[(108 + k*6 + c0)*1024 + pix];
            m1 = fmaxf(m1, lp[k]);
        }
        float se = 0.f;
        #pragma unroll
        for (int k=0;k<8;++k) se += __expf(lp[k]-m1);
        float lse = m1 + __logf(se);
        float xm = 0.f, mt = -1e30f;
        float t[8];
        #pragma unroll
        for (int k=0;k<8;++k){
            float lpn = lp[k] - lse;
            float u = (z0v - mu[k]) * __expf(-sv[k]);
            float au = fabsf(u);
            xm += __expf(lpn) * (1.f/(1.f+__expf(-u)));
            float lss = -(au + 2.f*log1pf(__expf(-au)));
            float tk = lpn - sv[k] + lss;
            t[k] = tk; mt = fmaxf(mt, tk);
        }
        float se2 = 0.f;
        #pragma unroll
        for (int k=0;k<8;++k) se2 += __expf(t[k]-mt);
        logacc += mt + __logf(se2);
        xm = fminf(fmaxf(xm, 1e-6f), 1.f-1e-6f);
        float lx = __logf(xm), l1x = log1pf(-xm);
        logacc += -lx - l1x;
        float aa = tanhf(a_raw)*als + abv;
        float z0n = (lx - l1x)*__expf(aa) + bco;
        logacc += aa;
        int oidx = (c0<3) ? ((b*3+c0)*64 + 2*i)*64 + 2*j
                          : ((b*3+(c0-3))*64 + 2*i+1)*64 + 2*j+1;
        out_z[oidx] = z0n;
    }

    #pragma unroll
    for (int o=32;o>0;o>>=1) logacc += __shfl_down(logacc, o, 64);
    __shared__ float part[4];
    if ((threadIdx.x&63)==0) part[threadIdx.x>>6] = logacc;
    __syncthreads();
    if (threadIdx.x==0){
        atomicAdd(out_log + b, part[0]+part[1]+part[2]+part[3]);
    }
}

extern "C" void kernel_launch(void* const* d_in, const int* in_sizes, int n_in,
                              void* d_out, int out_size, void* d_ws, size_t ws_size,
                              hipStream_t stream)
{
    const float* z     = (const float*)d_in[0];
    const float* logdf = (const float*)d_in[1];
    const float* c1w   = (const float*)d_in[2];
    const float* c1b   = (const float*)d_in[3];
    const float* gw    = (const float*)d_in[4];
    const float* gcb   = (const float*)d_in[5];
    const float* ln1g  = (const float*)d_in[6];
    const float* ln1b  = (const float*)d_in[7];
    const float* qkvw  = (const float*)d_in[8];
    const float* qkvb  = (const float*)d_in[9];
    const float* pw    = (const float*)d_in[10];
    const float* pbb   = (const float*)d_in[11];
    const float* ln2g  = (const float*)d_in[12];
    const float* ln2b  = (const float*)d_in[13];
    const float* c2w   = (const float*)d_in[14];
    const float* c2b   = (const float*)d_in[15];
    const float* als   = (const float*)d_in[16];
    const float* ab    = (const float*)d_in[17];

    float* out_z   = (float*)d_out;
    float* out_log = out_z + 786432;

    // workspace (float units), peak ~20.24M floats = 81 MB
    float* ws     = (float*)d_ws;
    u16*   x1b    = (u16*)(ws + 0);            // A: conv1 out bf16 (B,1024,96)
    u16*   xg_b   = (u16*)(ws + 3145728);      // B: gated-gconv out bf16
    u16*   xlnb   = (u16*)(ws + 6291456);      // C: LN1 out bf16 (live thru projm)
    u16*   Vtb    = (u16*)(ws + 9437184);      // D
    u16*   Ob     = (u16*)(ws + 12582912);     // E: attn out bf16
    u16*   x2b    = (u16*)(ws + 15728640);     // F: projm out bf16
    u16*   Qb     = x1b;                       // A reuse (x1b dead after gconv)
    u16*   Kbb    = xg_b;                      // B reuse (xg_b dead after lne1)
    u16*   xln2b  = xlnb;                      // C reuse (xlnb dead after projm)
    float* params = ws + 9437184;              // overlaps D/E/F (all dead by conv2)
    const size_t T = 19660800;
    float* gt1    = ws + T;                    // 98304
    float* bt1    = ws + T + 98304;
    float* gt2    = ws + T + 196608;
    float* bt2    = ws + T + 294912;
    float* part1  = ws + T + 393216;           // 1024
    float* part2  = ws + T + 394240;           // 1024
    float* stats1 = ws + T + 395264;           // 128
    float* stats2 = ws + T + 395392;           // 128
    u16*   Wg     = (u16*)(ws + T + 395520);   // [9][192][96]
    u16*   W2     = (u16*)(ws + T + 478464);   // [9][160][96]
    u16*   Wqkv   = (u16*)(ws + T + 547584);   // [288][96]
    u16*   Wproj  = (u16*)(ws + T + 561408);   // [192][96]

    k_wrep   <<<648 , 256, 0, stream>>>(gw,  Wg, 192, 192);
    k_wrep   <<<540 , 256, 0, stream>>>(c2w, W2, 156, 160);
    k_wrepm  <<<108 , 256, 0, stream>>>(qkvw, Wqkv, 288*96);
    k_wrepm  <<<72  , 256, 0, stream>>>(pw, Wproj, 192*96);
    k_wrepln <<<384 , 256, 0, stream>>>(ln1g, gt1);
    k_wrepln <<<384 , 256, 0, stream>>>(ln1b, bt1);
    k_wrepln <<<384 , 256, 0, stream>>>(ln2g, gt2);
    k_wrepln <<<384 , 256, 0, stream>>>(ln2b, bt2);
    k_conv1  <<<512 , 256, 0, stream>>>(z, c1w, c1b, x1b);
    k_gconv  <<<512 , 256, 0, stream>>>(x1b, Wg, gcb, xg_b, part1);
    k_stats  <<<1   ,  64, 0, stream>>>(part1, stats1);
    k_lne    <<<3072, 256, 0, stream>>>(xg_b, gt1, bt1, stats1, xlnb);
    k_qkvm   <<<512 , 256, 0, stream>>>(xlnb, Wqkv, qkvb, Qb, Kbb, Vtb);
    k_attn   <<<1024, 256, 0, stream>>>(Qb, Kbb, Vtb, Ob);
    k_projm  <<<512 , 256, 0, stream>>>(Ob, Wproj, pbb, xlnb, x2b, part2);
    k_stats  <<<1   ,  64, 0, stream>>>(part2, stats2);
    k_lne    <<<3072, 256, 0, stream>>>(x2b, gt2, bt2, stats2, xln2b);
    k_conv2m <<<512 , 256, 0, stream>>>(xln2b, W2, c2b, params);
    k_initlog<<<1   ,  64, 0, stream>>>(logdf, out_log);
    k_mix    <<<256 , 256, 0, stream>>>(z, params, als, ab, out_z, out_log);
}